// Round 10
// baseline (267.232 us; speedup 1.0000x reference)
//
#include <hip/hip_runtime.h>
#include <cstdint>
#include <cstddef>

typedef __attribute__((ext_vector_type(8))) short bf16x8;
typedef __attribute__((ext_vector_type(4))) short bf16x4;
typedef __attribute__((ext_vector_type(4))) float f32x4;
typedef __attribute__((ext_vector_type(4))) unsigned int u32x4;
typedef __attribute__((ext_vector_type(2))) unsigned int u32x2;

__device__ inline unsigned short f2b(float f){
  unsigned int u = __float_as_uint(f);
  u += 0x7fffu + ((u >> 16) & 1u);
  return (unsigned short)(u >> 16);
}
// pack two fp32 -> bf16 pair via v_perm (probs >= 0, round-half-up)
__device__ inline unsigned int pk2(float a, float b){
  unsigned int ua = __float_as_uint(a) + 0x8000u;
  unsigned int ub = __float_as_uint(b) + 0x8000u;
  return __builtin_amdgcn_perm(ub, ua, 0x07060302u);
}
// async global->LDS, 16B/lane; LDS dest = wave-uniform base + lane*16
__device__ inline void gl2lds16(const void* g, void* l){
  __builtin_amdgcn_global_load_lds(
      (const __attribute__((address_space(1))) unsigned int*)g,
      (__attribute__((address_space(3))) unsigned int*)l, 16, 0, 0);
}

#define QSCALE 0.18033688011112042f   // 0.125 * log2(e): softmax in log2 domain

// ---------------------------------------------------------------------------
// Fused prologue (unchanged from R7): wcvt | ln->bf16 | ctx in one dispatch.
// ---------------------------------------------------------------------------
__global__ __launch_bounds__(256) void prologue_kernel(
    const float* __restrict__ Wq, const float* __restrict__ Wkv,
    const float* __restrict__ Wout,
    unsigned short* __restrict__ Wqkv_t, unsigned short* __restrict__ Wout_t,
    const float* __restrict__ X, const float* __restrict__ G,
    const float* __restrict__ Bb, unsigned short* __restrict__ xn,
    const float* __restrict__ Cemb, const float* __restrict__ cG,
    const float* __restrict__ cBb, const float* __restrict__ Wctx,
    const float* __restrict__ bctx, const float* __restrict__ nullkv,
    unsigned short* __restrict__ kext, unsigned short* __restrict__ vext_t)
{
  __shared__ __align__(16) char fsm[9216];
  int bid = blockIdx.x;
  int t = threadIdx.x;

  if (bid < 1024){
    short* tile = (short*)fsm;
    int cg0 = (bid & 63) * 64;
    int kt  = (bid >> 6) * 64;
    const float* src; int ld; int col0; unsigned short* dst; int drow0;
    if (cg0 < 1024)      { src = Wq;   ld = 1024; col0 = cg0;        dst = Wqkv_t; drow0 = cg0; }
    else if (cg0 < 3072) { src = Wkv;  ld = 2048; col0 = cg0 - 1024; dst = Wqkv_t; drow0 = cg0; }
    else                 { src = Wout; ld = 1024; col0 = cg0 - 3072; dst = Wout_t; drow0 = cg0 - 3072; }
    #pragma unroll
    for (int i = 0; i < 16; ++i){
      int lin = t + 256*i;
      int k = lin >> 6, c = lin & 63;
      tile[k*72 + c] = (short)f2b(src[(size_t)(kt + k)*ld + col0 + c]);
    }
    __syncthreads();
    #pragma unroll
    for (int i = 0; i < 16; ++i){
      int lin = t + 256*i;
      int c = lin >> 6, k = lin & 63;
      dst[(size_t)(drow0 + c)*1024 + kt + k] = (unsigned short)tile[k*72 + c];
    }
  } else if (bid < 5120){
    int row = bid - 1024;
    float* red = (float*)fsm;
    float4 x = ((const float4*)(X + (size_t)row*1024))[t];
    float s  = x.x + x.y + x.z + x.w;
    float s2 = x.x*x.x + x.y*x.y + x.z*x.z + x.w*x.w;
    #pragma unroll
    for (int o = 32; o > 0; o >>= 1){ s += __shfl_down(s, o); s2 += __shfl_down(s2, o); }
    int w = t >> 6;
    if ((t & 63) == 0){ red[w] = s; red[4 + w] = s2; }
    __syncthreads();
    float mu  = (red[0]+red[1]+red[2]+red[3]) * (1.0f/1024.0f);
    float var = (red[4]+red[5]+red[6]+red[7]) * (1.0f/1024.0f) - mu*mu;
    float rstd = rsqrtf(var + 1e-5f);
    float4 g = ((const float4*)G)[t];
    float4 b = ((const float4*)Bb)[t];
    ushort4 u;
    u.x = f2b((x.x-mu)*rstd*g.x + b.x);
    u.y = f2b((x.y-mu)*rstd*g.y + b.y);
    u.z = f2b((x.z-mu)*rstd*g.z + b.z);
    u.w = f2b((x.w-mu)*rstd*g.w + b.w);
    ((ushort4*)xn)[(size_t)row*256 + t] = u;
  } else {
    int row = bid - 5120;            // 0..255 (b*128 + m)
    int b = row >> 7, m = row & 127;
    bool act = t < 128;
    float* red  = (float*)fsm;
    float* xns  = (float*)(fsm + 16);
    if (act && row < 128){
      int b2 = row >> 6, fr = row & 63;
      int frow = (fr == 0) ? 0 : (128 + fr);
      if (t < 64){
        kext[((size_t)b2*192 + frow)*64 + t] = (frow == 0) ? f2b(nullkv[t]) : (unsigned short)0;
      } else {
        int d = t - 64;
        vext_t[((size_t)b2*64 + d)*192 + frow] = (frow == 0) ? f2b(nullkv[64 + d]) : (unsigned short)0;
      }
    }
    const float* xr = Cemb + (size_t)row*768;
    float v[6]; float s = 0.f, s2 = 0.f;
    if (act){
      #pragma unroll
      for (int j = 0; j < 6; ++j){ float xv = xr[t + 128*j]; v[j] = xv; s += xv; s2 += xv*xv; }
      #pragma unroll
      for (int o = 32; o > 0; o >>= 1){ s += __shfl_down(s, o); s2 += __shfl_down(s2, o); }
      int w = t >> 6;
      if ((t & 63) == 0){ red[w] = s; red[2 + w] = s2; }
    }
    __syncthreads();
    if (act){
      float mu  = (red[0]+red[1]) * (1.0f/768.0f);
      float var = (red[2]+red[3]) * (1.0f/768.0f) - mu*mu;
      float rstd = rsqrtf(var + 1e-5f);
      #pragma unroll
      for (int j = 0; j < 6; ++j){ int c = t + 128*j; xns[c] = (v[j]-mu)*rstd*cG[c] + cBb[c]; }
    }
    __syncthreads();
    if (act){
      float acc = bctx[t];
      #pragma unroll 8
      for (int j = 0; j < 768; ++j) acc += xns[j] * Wctx[j*128 + t];
      unsigned short hv = f2b(acc);
      if (t < 64) kext[((size_t)b*192 + 1 + m)*64 + t] = hv;
      else        vext_t[((size_t)b*64 + (t - 64))*192 + 1 + m] = hv;
    }
  }
}

// ---------------------------------------------------------------------------
// Final LayerNorm over 1024 cols; input = P0 + P1 (split-K partial sums).
// ---------------------------------------------------------------------------
__global__ __launch_bounds__(256) void ln1024f_kernel(
    const float* __restrict__ P0, const float* __restrict__ P1,
    const float* __restrict__ G, const float* __restrict__ Bb,
    float* __restrict__ out)
{
  int row = blockIdx.x, t = threadIdx.x;
  float4 xa = ((const float4*)(P0 + (size_t)row*1024))[t];
  float4 xb = ((const float4*)(P1 + (size_t)row*1024))[t];
  float4 x;
  x.x = xa.x + xb.x; x.y = xa.y + xb.y; x.z = xa.z + xb.z; x.w = xa.w + xb.w;
  float s  = x.x + x.y + x.z + x.w;
  float s2 = x.x*x.x + x.y*x.y + x.z*x.z + x.w*x.w;
  #pragma unroll
  for (int o = 32; o > 0; o >>= 1){ s += __shfl_down(s, o); s2 += __shfl_down(s2, o); }
  __shared__ float red[8];
  int w = t >> 6;
  if ((t & 63) == 0){ red[w] = s; red[4 + w] = s2; }
  __syncthreads();
  float mu  = (red[0]+red[1]+red[2]+red[3]) * (1.0f/1024.0f);
  float var = (red[4]+red[5]+red[6]+red[7]) * (1.0f/1024.0f) - mu*mu;
  float rstd = rsqrtf(var + 1e-5f);
  float4 g = ((const float4*)G)[t];
  float4 b = ((const float4*)Bb)[t];
  float4 y;
  y.x = (x.x-mu)*rstd*g.x + b.x;
  y.y = (x.y-mu)*rstd*g.y + b.y;
  y.z = (x.z-mu)*rstd*g.z + b.z;
  y.w = (x.w-mu)*rstd*g.w + b.w;
  ((float4*)out)[(size_t)row*256 + t] = y;
}

// ---------------------------------------------------------------------------
// bt-GEMM mainloop, K-range parameterized (split-K support).
// ---------------------------------------------------------------------------
#define GEMM_MAINLOOP_K(A_, Bt_, tM_, tN_, KLO_, KHI_)                          \
  __shared__ __align__(16) short sA[128*64];                                    \
  __shared__ __align__(16) short sB[128*64];                                    \
  int t = threadIdx.x, w = t >> 6, lane = t & 63;                               \
  int wm = w & 1, wn = w >> 1, lm = lane & 15, q = lane >> 4;                   \
  int grow = lane >> 3;                                                         \
  int gchk = ((lane & 7) ^ grow) << 3;                                          \
  f32x4 acc[4][4] = {};                                                         \
  const unsigned short* Aw = A_ + (size_t)(tM_ + w*32 + grow)*1024 + gchk;      \
  const unsigned short* Bw = Bt_ + (size_t)(tN_ + w*32 + grow)*1024 + gchk;     \
  for (int kk = (KLO_); kk < (KHI_); kk += 64){                                 \
    __syncthreads();                                                            \
    gl2lds16(Aw + kk,            &sA[(w*32     )*64]);                          \
    gl2lds16(Aw + kk +  8*1024,  &sA[(w*32 +  8)*64]);                          \
    gl2lds16(Aw + kk + 16*1024,  &sA[(w*32 + 16)*64]);                          \
    gl2lds16(Aw + kk + 24*1024,  &sA[(w*32 + 24)*64]);                          \
    gl2lds16(Bw + kk,            &sB[(w*32     )*64]);                          \
    gl2lds16(Bw + kk +  8*1024,  &sB[(w*32 +  8)*64]);                          \
    gl2lds16(Bw + kk + 16*1024,  &sB[(w*32 + 16)*64]);                          \
    gl2lds16(Bw + kk + 24*1024,  &sB[(w*32 + 24)*64]);                          \
    __syncthreads();                                                            \
    bf16x8 af[4][2], bfr[4][2];                                                 \
    _Pragma("unroll")                                                           \
    for (int i = 0; i < 4; ++i){                                                \
      int ra = wm*64 + i*16 + lm, rb = wn*64 + i*16 + lm;                       \
      _Pragma("unroll")                                                         \
      for (int hh = 0; hh < 2; ++hh){                                           \
        int sw = ((hh*4 + q) ^ (lm & 7)) << 3;                                  \
        af[i][hh]  = *(const bf16x8*)(&sA[ra*64 + sw]);                         \
        bfr[i][hh] = *(const bf16x8*)(&sB[rb*64 + sw]);                         \
      }                                                                         \
    }                                                                           \
    _Pragma("unroll")                                                           \
    for (int hh = 0; hh < 2; ++hh)                                              \
      _Pragma("unroll")                                                         \
      for (int i = 0; i < 4; ++i)                                               \
        _Pragma("unroll")                                                       \
        for (int j = 0; j < 4; ++j)                                             \
          acc[i][j] = __builtin_amdgcn_mfma_f32_16x16x32_bf16(af[i][hh], bfr[j][hh], acc[i][j], 0, 0, 0); \
  }

#define GEMM_MAINLOOP(A_, Bt_, tM_, tN_) GEMM_MAINLOOP_K(A_, Bt_, tM_, tN_, 0, 1024)

// QKV GEMM (1D grid 768). XCD swizzle: 8 M-tiles x 12 N-tiles per XCD.
__global__ __launch_bounds__(256) void gemm_qkv_kernel(
    const unsigned short* __restrict__ A, const unsigned short* __restrict__ Bt,
    unsigned short* __restrict__ Qb, unsigned short* __restrict__ Kb,
    unsigned short* __restrict__ VtG)
{
  int id = blockIdx.x;
  int xcd = id & 7, r = id >> 3;          // r in [0,96)
  int tM = ((xcd >> 1)*8 + (r & 7)) * 128;
  int tN = ((xcd & 1)*12 + (r >> 3)) * 128;   // [0,24) -> Q/K/V regions
  GEMM_MAINLOOP(A, Bt, tM, tN)
  if (tN < 1024){                 // Q region
    #pragma unroll
    for (int i = 0; i < 4; ++i){
      int R0 = tM + wm*64 + i*16 + q*4;
      int b = R0 >> 11, n = R0 & 2047;
      #pragma unroll
      for (int j = 0; j < 4; ++j){
        int Cg = tN + wn*64 + j*16 + lm;
        int h = Cg >> 6, d = Cg & 63;
        size_t base = ((((size_t)(b*16 + h) << 11) | n) << 6) + d;
        #pragma unroll
        for (int rr = 0; rr < 4; ++rr)
          Qb[base + (size_t)rr*64] = f2b(acc[i][j][rr] * QSCALE);
      }
    }
  } else if (tN < 2048){          // K region
    #pragma unroll
    for (int i = 0; i < 4; ++i){
      int R0 = tM + wm*64 + i*16 + q*4;
      int b = R0 >> 11, n = R0 & 2047;
      #pragma unroll
      for (int j = 0; j < 4; ++j){
        int c2 = tN - 1024 + wn*64 + j*16 + lm;
        int h = c2 >> 6, d = c2 & 63;
        size_t base = ((((size_t)(b*16 + h) << 11) | n) << 6) + d;
        #pragma unroll
        for (int rr = 0; rr < 4; ++rr)
          Kb[base + (size_t)rr*64] = f2b(acc[i][j][rr]);
      }
    }
  } else {                        // V region -> transposed, packed 8B stores
    #pragma unroll
    for (int i = 0; i < 4; ++i){
      int R0 = tM + wm*64 + i*16 + q*4;
      int b = R0 >> 11, n = R0 & 2047;
      #pragma unroll
      for (int j = 0; j < 4; ++j){
        int c2 = tN - 2048 + wn*64 + j*16 + lm;
        int h = c2 >> 6, d = c2 & 63;
        ushort4 u;
        u.x = f2b(acc[i][j][0]); u.y = f2b(acc[i][j][1]);
        u.z = f2b(acc[i][j][2]); u.w = f2b(acc[i][j][3]);
        *(ushort4*)(VtG + ((size_t)(b*16 + h)*64 + d)*2048 + n) = u;
      }
    }
  }
}

// Out-proj GEMM, split-K 2-way (kept from R8: non-attn time 198.5 -> 193.9).
__global__ __launch_bounds__(256) void gemm_out_kernel(
    const unsigned short* __restrict__ A, const unsigned short* __restrict__ Bt,
    float* __restrict__ C0, float* __restrict__ C1)
{
  int id = blockIdx.x;
  int xcd = id & 7, r = id >> 3;          // r in [0,64)
  int ks = r & 1;                          // K slice
  int r2 = r >> 1;                         // [0,32)
  int tM = ((r2 & 3)*8 + xcd) * 128;
  int tN = (r2 >> 2) * 128;                // [0,8)
  float* C = ks ? C1 : C0;
  GEMM_MAINLOOP_K(A, Bt, tM, tN, ks*512, ks*512 + 512)
  #pragma unroll
  for (int i = 0; i < 4; ++i){
    int R0 = tM + wm*64 + i*16 + q*4;
    #pragma unroll
    for (int j = 0; j < 4; ++j){
      int Cg = tN + wn*64 + j*16 + lm;
      #pragma unroll
      for (int rr = 0; rr < 4; ++rr)
        C[(size_t)(R0 + rr)*1024 + Cg] = acc[i][j][rr];
    }
  }
}

// ---------------------------------------------------------------------------
// Flash attention — R9's swizzled layouts + R8's 64-query geometry, retried
// now that LDS permits the 3rd block/CU:
//   R8 failed at LDS 54272 (3x54272=162816, 1KB slack -> runtime reservation
//   blocked block 3; occupancy stayed 18.6%, doubled staging cost +8.5us).
//   R9's swizzle shrank LDS to 40960: 3x40960=122880, 40KB slack -> 3
//   blocks/CU = 12 waves/CU (+50% latency hiding on a latency-bound kernel).
//   VGPR ~84 in this geometry (R8 measured) -> not limiting.
// Grid = 32 bh * 32 chunks = 1024 blocks (xcd-swizzled), 64 queries/block,
// 4 waves in 2 pairs (18/17 key tiles), additive no-max log2-softmax.
// LDS carve (40960 B): [0,16384) K | [16384,32768) Vt | [32768,40960) P.
// K/V: 64x64 shorts, granule g at g^(row&7) (write rsw=r0&7, read esw=lm&7).
// Merge overlay [0,18432) after final barrier (K dead; spills into Vt, dead).
// KILL CRITERION: occupancy <=19% -> revert to R9 128-query geometry.
// ---------------------------------------------------------------------------
__global__ __launch_bounds__(256, 2) void attn_kernel(
    const unsigned short* __restrict__ Qb, const unsigned short* __restrict__ Kb,
    const unsigned short* __restrict__ VtG, const unsigned short* __restrict__ kext,
    const unsigned short* __restrict__ vext_t, unsigned short* __restrict__ Ob)
{
  __shared__ __align__(16) char smem[40960];
  int id = blockIdx.x;
  int xcd = id & 7, slot = id >> 3;              // slot in [0,128)
  int bh = xcd*4 + (slot >> 5);                  // 4 bh per XCD for L2 locality
  int q64 = slot & 31;                           // 64-query chunk
  int b = bh >> 4, h = bh & 15;
  int t = threadIdx.x, w = t >> 6, lane = t & 63;
  int p = w >> 1, lw = w & 1;
  int lm = lane & 15, q = lane >> 4;
  int esw = lm & 7;                              // read-side swizzle key

  short* myK = (short*)(smem + p*8192);
  short* myV = (short*)(smem + 16384 + p*8192);
  short* pw  = (short*)(smem + 32768 + w*2048);

  const unsigned short* Qbase = Qb + ((size_t)bh*2048 + q64*64 + lw*32)*64;
  bf16x8 qf[2][2];
  #pragma unroll
  for (int qq = 0; qq < 2; ++qq){
    qf[qq][0] = *(const bf16x8*)(Qbase + (size_t)(qq*16 + lm)*64 + q*8);
    qf[qq][1] = *(const bf16x8*)(Qbase + (size_t)(qq*16 + lm)*64 + q*8 + 32);
  }

  f32x4 o[4][2] = {};                            // [ds][qq]
  float l_i[2] = {0.f, 0.f};

  // staging within the pair: 128 threads, row r0, 32-short half c0
  int pt = t & 127;
  int r0 = pt >> 1, c0 = (pt & 1) << 5;
  int rsw = r0 & 7;                              // write-side swizzle key
  const int t0 = p ? 18 : 0;
  const int t1 = p ? 35 : 18;

  u32x4 kr[4], vr[4];
  {
    const unsigned short* kp = Kb + ((size_t)bh*2048 + t0*64 + r0)*64 + c0;
    const unsigned short* vp = VtG + ((size_t)bh*64 + r0)*2048 + t0*64 + c0;
    #pragma unroll
    for (int jj = 0; jj < 4; ++jj){
      kr[jj] = *(const u32x4*)(kp + 8*jj);
      vr[jj] = *(const u32x4*)(vp + 8*jj);
    }
  }

  for (int it = 0; it < 18; ++it){
    int tile = t0 + it;
    bool valid = tile < t1;
    __syncthreads();
    if (valid){
      #pragma unroll
      for (int jj = 0; jj < 4; ++jj){
        int gsw = ((((pt & 1) << 2) | jj) ^ rsw) << 3;
        *(u32x4*)(&myK[r0*64 + gsw]) = kr[jj];
        *(u32x4*)(&myV[r0*64 + gsw]) = vr[jj];
      }
    }
    __syncthreads();

    int nt = tile + 1;
    if (nt < t1){                                // prefetch next tile
      bool ext = nt >= 32;
      int kb = ext ? (nt - 32)*64 : nt*64;
      const unsigned short* kp = ext ? (kext + ((size_t)b*192 + kb + r0)*64 + c0)
                                     : (Kb + ((size_t)bh*2048 + kb + r0)*64 + c0);
      const unsigned short* vp = ext ? (vext_t + ((size_t)b*64 + r0)*192 + kb + c0)
                                     : (VtG + ((size_t)bh*64 + r0)*2048 + kb + c0);
      #pragma unroll
      for (int jj = 0; jj < 4; ++jj){
        kr[jj] = *(const u32x4*)(kp + 8*jj);
        vr[jj] = *(const u32x4*)(vp + 8*jj);
      }
    }
    if (!valid) continue;                        // barriers already passed

    bf16x8 kf[4][2];
    #pragma unroll
    for (int st = 0; st < 4; ++st){
      kf[st][0] = *(const bf16x8*)(&myK[(st*16 + lm)*64 + ((q       ^ esw) << 3)]);
      kf[st][1] = *(const bf16x8*)(&myK[(st*16 + lm)*64 + (((4 + q) ^ esw) << 3)]);
    }

    f32x4 s[2][4];
    #pragma unroll
    for (int qh = 0; qh < 2; ++qh){
      #pragma unroll
      for (int st = 0; st < 4; ++st){
        f32x4 z = {};
        z = __builtin_amdgcn_mfma_f32_16x16x32_bf16(kf[st][0], qf[qh][0], z, 0, 0, 0);
        s[qh][st] = __builtin_amdgcn_mfma_f32_16x16x32_bf16(kf[st][1], qf[qh][1], z, 0, 0, 0);
      }
    }
    if (tile == 34){                             // keys 128..191: only 128 valid
      #pragma unroll
      for (int qh = 0; qh < 2; ++qh)
        #pragma unroll
        for (int st = 0; st < 4; ++st)
          #pragma unroll
          for (int rr = 0; rr < 4; ++rr){
            int key = 128 + st*16 + q*4 + rr;
            if (key >= 129) s[qh][st][rr] = -1e30f;
          }
    }
    bf16x8 pb[2][2];
    #pragma unroll
    for (int qh = 0; qh < 2; ++qh){              // per-qh: exp, pack->pw, read
      float sm = 0.f;
      #pragma unroll
      for (int st = 0; st < 4; ++st)
        #pragma unroll
        for (int rr = 0; rr < 4; ++rr){
          float pv = __builtin_amdgcn_exp2f(s[qh][st][rr]);
          s[qh][st][rr] = pv; sm += pv;
        }
      l_i[qh] += sm;
      #pragma unroll
      for (int st = 0; st < 4; ++st){
        u32x2 pkd;
        pkd[0] = pk2(s[qh][st][0], s[qh][st][1]);
        pkd[1] = pk2(s[qh][st][2], s[qh][st][3]);
        int gsw = ((((st << 1) | (q >> 1)) ^ esw) << 3) + ((q & 1) << 2);
        *(u32x2*)(&pw[lm*64 + gsw]) = pkd;
      }
      // read back (own-wave region, in-order DS pipe -> no barrier)
      bf16x4 a0 = *(const bf16x4*)(&pw[lm*64 + ((q       ^ esw) << 3)]);
      bf16x4 a1 = *(const bf16x4*)(&pw[lm*64 + ((q       ^ esw) << 3) + 4]);
      bf16x4 a2 = *(const bf16x4*)(&pw[lm*64 + (((4 + q) ^ esw) << 3)]);
      bf16x4 a3 = *(const bf16x4*)(&pw[lm*64 + (((4 + q) ^ esw) << 3) + 4]);
      pb[qh][0] = __builtin_shufflevector(a0, a1, 0,1,2,3,4,5,6,7);
      pb[qh][1] = __builtin_shufflevector(a2, a3, 0,1,2,3,4,5,6,7);
    }
    #pragma unroll
    for (int ds = 0; ds < 4; ++ds){
      bf16x8 af0 = *(const bf16x8*)(&myV[(ds*16 + lm)*64 + ((q       ^ esw) << 3)]);
      bf16x8 af1 = *(const bf16x8*)(&myV[(ds*16 + lm)*64 + (((4 + q) ^ esw) << 3)]);
      #pragma unroll
      for (int qh = 0; qh < 2; ++qh){
        o[ds][qh] = __builtin_amdgcn_mfma_f32_16x16x32_bf16(af0, pb[qh][0], o[ds][qh], 0, 0, 0);
        o[ds][qh] = __builtin_amdgcn_mfma_f32_16x16x32_bf16(af1, pb[qh][1], o[ds][qh], 0, 0, 0);
      }
    }
  }

  // ---- merge the two key-halves (additive: no rescale needed) ----
  // overlay at smem offset 0: 2 lw-slots x 64 lanes x 36 floats = 18432 B
  // (K region dead; spills into Vt region, also dead past this barrier)
  float* mb = (float*)smem;
  float* reg = mb + lw*2304 + lane*36;
  __syncthreads();                               // all KV/P reads done
  if (p == 1){
    #pragma unroll
    for (int ds = 0; ds < 4; ++ds)
      #pragma unroll
      for (int qq = 0; qq < 2; ++qq)
        *(f32x4*)(reg + (ds*2 + qq)*4) = o[ds][qq];
    #pragma unroll
    for (int qq = 0; qq < 2; ++qq) reg[32 + qq] = l_i[qq];
  }
  __syncthreads();
  if (p == 0){
    #pragma unroll
    for (int qq = 0; qq < 2; ++qq){
      #pragma unroll
      for (int ds = 0; ds < 4; ++ds){
        f32x4 ov = *(const f32x4*)(reg + (ds*2 + qq)*4);
        o[ds][qq] += ov;
      }
      float l = l_i[qq] + reg[32 + qq];
      l += __shfl_xor(l, 16);
      l += __shfl_xor(l, 32);
      float inv = 1.0f / l;
      int n = q64*64 + lw*32 + qq*16 + lm;
      size_t base = ((size_t)b*2048 + n)*1024 + h*64 + q*4;
      #pragma unroll
      for (int ds = 0; ds < 4; ++ds){
        ushort4 u;
        u.x = f2b(o[ds][qq][0] * inv); u.y = f2b(o[ds][qq][1] * inv);
        u.z = f2b(o[ds][qq][2] * inv); u.w = f2b(o[ds][qq][3] * inv);
        *(ushort4*)(Ob + base + ds*16) = u;
      }
    }
  }
}

// ---------------------------------------------------------------------------
extern "C" void kernel_launch(void* const* d_in, const int* in_sizes, int n_in,
                              void* d_out, int out_size, void* d_ws, size_t ws_size,
                              hipStream_t stream)
{
  const float* x       = (const float*)d_in[0];
  const float* c_emb   = (const float*)d_in[1];
  const float* ln_g    = (const float*)d_in[2];
  const float* ln_b    = (const float*)d_in[3];
  const float* ctx_g   = (const float*)d_in[4];
  const float* ctx_b   = (const float*)d_in[5];
  const float* W_ctx   = (const float*)d_in[6];
  const float* b_ctx   = (const float*)d_in[7];
  const float* W_q     = (const float*)d_in[8];
  const float* W_kv    = (const float*)d_in[9];
  const float* null_kv = (const float*)d_in[10];
  const float* W_out   = (const float*)d_in[11];
  const float* oln_g   = (const float*)d_in[12];
  const float* oln_b   = (const float*)d_in[13];
  float* out = (float*)d_out;

  char* p = (char*)d_ws;
  unsigned short* xn     = (unsigned short*)p; p += (size_t)4096*1024*2;
  unsigned short* Wqkv_t = (unsigned short*)p; p += (size_t)3072*1024*2;
  unsigned short* Wout_t = (unsigned short*)p; p += (size_t)1024*1024*2;
  unsigned short* Qb     = (unsigned short*)p; p += (size_t)32*2048*64*2;
  unsigned short* Kb     = (unsigned short*)p; p += (size_t)32*2048*64*2;
  unsigned short* VtG    = (unsigned short*)p; p += (size_t)32*64*2048*2;
  unsigned short* kext   = (unsigned short*)p; p += (size_t)2*192*64*2;
  unsigned short* vext_t = (unsigned short*)p; p += (size_t)2*64*192*2;
  unsigned short* aout   = (unsigned short*)p; p += (size_t)4096*1024*2;
  float*          ptmp   = (float*)p;          p += (size_t)4096*1024*4;
  // split-K partial #2 overlays Qb+Kb (16 MB, dead after attn completes)
  float*          ptmp1  = (float*)Qb;

  prologue_kernel<<<5376, 256, 0, stream>>>(
      W_q, W_kv, W_out, Wqkv_t, Wout_t,
      x, ln_g, ln_b, xn,
      c_emb, ctx_g, ctx_b, W_ctx, b_ctx, null_kv, kext, vext_t);
  gemm_qkv_kernel<<<768, 256, 0, stream>>>(xn, Wqkv_t, Qb, Kb, VtG);
  attn_kernel<<<1024, 256, 0, stream>>>(Qb, Kb, VtG, kext, vext_t, aout);
  gemm_out_kernel<<<512, 256, 0, stream>>>(aout, Wout_t, ptmp, ptmp1);
  ln1024f_kernel<<<4096, 256, 0, stream>>>(ptmp, ptmp1, oln_g, oln_b, out);
}

// Round 13
// 263.593 us; speedup vs baseline: 1.0138x; 1.0138x over previous
//
#include <hip/hip_runtime.h>
#include <cstdint>
#include <cstddef>

typedef __attribute__((ext_vector_type(8))) short bf16x8;
typedef __attribute__((ext_vector_type(4))) short bf16x4;
typedef __attribute__((ext_vector_type(4))) float f32x4;
typedef __attribute__((ext_vector_type(4))) unsigned int u32x4;
typedef __attribute__((ext_vector_type(2))) unsigned int u32x2;

__device__ inline unsigned short f2b(float f){
  unsigned int u = __float_as_uint(f);
  u += 0x7fffu + ((u >> 16) & 1u);
  return (unsigned short)(u >> 16);
}
// pack two fp32 -> bf16 pair via v_perm (probs >= 0, round-half-up)
__device__ inline unsigned int pk2(float a, float b){
  unsigned int ua = __float_as_uint(a) + 0x8000u;
  unsigned int ub = __float_as_uint(b) + 0x8000u;
  return __builtin_amdgcn_perm(ub, ua, 0x07060302u);
}
// async global->LDS, 16B/lane; LDS dest = wave-uniform base + lane*16
__device__ inline void gl2lds16(const void* g, void* l){
  __builtin_amdgcn_global_load_lds(
      (const __attribute__((address_space(1))) unsigned int*)g,
      (__attribute__((address_space(3))) unsigned int*)l, 16, 0, 0);
}

#define QSCALE 0.18033688011112042f   // 0.125 * log2(e): softmax in log2 domain

// ---------------------------------------------------------------------------
// Fused prologue (unchanged from R7): wcvt | ln->bf16 | ctx in one dispatch.
// ---------------------------------------------------------------------------
__global__ __launch_bounds__(256) void prologue_kernel(
    const float* __restrict__ Wq, const float* __restrict__ Wkv,
    const float* __restrict__ Wout,
    unsigned short* __restrict__ Wqkv_t, unsigned short* __restrict__ Wout_t,
    const float* __restrict__ X, const float* __restrict__ G,
    const float* __restrict__ Bb, unsigned short* __restrict__ xn,
    const float* __restrict__ Cemb, const float* __restrict__ cG,
    const float* __restrict__ cBb, const float* __restrict__ Wctx,
    const float* __restrict__ bctx, const float* __restrict__ nullkv,
    unsigned short* __restrict__ kext, unsigned short* __restrict__ vext_t)
{
  __shared__ __align__(16) char fsm[9216];
  int bid = blockIdx.x;
  int t = threadIdx.x;

  if (bid < 1024){
    short* tile = (short*)fsm;
    int cg0 = (bid & 63) * 64;
    int kt  = (bid >> 6) * 64;
    const float* src; int ld; int col0; unsigned short* dst; int drow0;
    if (cg0 < 1024)      { src = Wq;   ld = 1024; col0 = cg0;        dst = Wqkv_t; drow0 = cg0; }
    else if (cg0 < 3072) { src = Wkv;  ld = 2048; col0 = cg0 - 1024; dst = Wqkv_t; drow0 = cg0; }
    else                 { src = Wout; ld = 1024; col0 = cg0 - 3072; dst = Wout_t; drow0 = cg0 - 3072; }
    #pragma unroll
    for (int i = 0; i < 16; ++i){
      int lin = t + 256*i;
      int k = lin >> 6, c = lin & 63;
      tile[k*72 + c] = (short)f2b(src[(size_t)(kt + k)*ld + col0 + c]);
    }
    __syncthreads();
    #pragma unroll
    for (int i = 0; i < 16; ++i){
      int lin = t + 256*i;
      int c = lin >> 6, k = lin & 63;
      dst[(size_t)(drow0 + c)*1024 + kt + k] = (unsigned short)tile[k*72 + c];
    }
  } else if (bid < 5120){
    int row = bid - 1024;
    float* red = (float*)fsm;
    float4 x = ((const float4*)(X + (size_t)row*1024))[t];
    float s  = x.x + x.y + x.z + x.w;
    float s2 = x.x*x.x + x.y*x.y + x.z*x.z + x.w*x.w;
    #pragma unroll
    for (int o = 32; o > 0; o >>= 1){ s += __shfl_down(s, o); s2 += __shfl_down(s2, o); }
    int w = t >> 6;
    if ((t & 63) == 0){ red[w] = s; red[4 + w] = s2; }
    __syncthreads();
    float mu  = (red[0]+red[1]+red[2]+red[3]) * (1.0f/1024.0f);
    float var = (red[4]+red[5]+red[6]+red[7]) * (1.0f/1024.0f) - mu*mu;
    float rstd = rsqrtf(var + 1e-5f);
    float4 g = ((const float4*)G)[t];
    float4 b = ((const float4*)Bb)[t];
    ushort4 u;
    u.x = f2b((x.x-mu)*rstd*g.x + b.x);
    u.y = f2b((x.y-mu)*rstd*g.y + b.y);
    u.z = f2b((x.z-mu)*rstd*g.z + b.z);
    u.w = f2b((x.w-mu)*rstd*g.w + b.w);
    ((ushort4*)xn)[(size_t)row*256 + t] = u;
  } else {
    int row = bid - 5120;            // 0..255 (b*128 + m)
    int b = row >> 7, m = row & 127;
    bool act = t < 128;
    float* red  = (float*)fsm;
    float* xns  = (float*)(fsm + 16);
    if (act && row < 128){
      int b2 = row >> 6, fr = row & 63;
      int frow = (fr == 0) ? 0 : (128 + fr);
      if (t < 64){
        kext[((size_t)b2*192 + frow)*64 + t] = (frow == 0) ? f2b(nullkv[t]) : (unsigned short)0;
      } else {
        int d = t - 64;
        vext_t[((size_t)b2*64 + d)*192 + frow] = (frow == 0) ? f2b(nullkv[64 + d]) : (unsigned short)0;
      }
    }
    const float* xr = Cemb + (size_t)row*768;
    float v[6]; float s = 0.f, s2 = 0.f;
    if (act){
      #pragma unroll
      for (int j = 0; j < 6; ++j){ float xv = xr[t + 128*j]; v[j] = xv; s += xv; s2 += xv*xv; }
      #pragma unroll
      for (int o = 32; o > 0; o >>= 1){ s += __shfl_down(s, o); s2 += __shfl_down(s2, o); }
      int w = t >> 6;
      if ((t & 63) == 0){ red[w] = s; red[2 + w] = s2; }
    }
    __syncthreads();
    if (act){
      float mu  = (red[0]+red[1]) * (1.0f/768.0f);
      float var = (red[2]+red[3]) * (1.0f/768.0f) - mu*mu;
      float rstd = rsqrtf(var + 1e-5f);
      #pragma unroll
      for (int j = 0; j < 6; ++j){ int c = t + 128*j; xns[c] = (v[j]-mu)*rstd*cG[c] + cBb[c]; }
    }
    __syncthreads();
    if (act){
      float acc = bctx[t];
      #pragma unroll 8
      for (int j = 0; j < 768; ++j) acc += xns[j] * Wctx[j*128 + t];
      unsigned short hv = f2b(acc);
      if (t < 64) kext[((size_t)b*192 + 1 + m)*64 + t] = hv;
      else        vext_t[((size_t)b*64 + (t - 64))*192 + 1 + m] = hv;
    }
  }
}

// ---------------------------------------------------------------------------
// Final LayerNorm over 1024 cols; input = P0 + P1 (split-K partial sums).
// ---------------------------------------------------------------------------
__global__ __launch_bounds__(256) void ln1024f_kernel(
    const float* __restrict__ P0, const float* __restrict__ P1,
    const float* __restrict__ G, const float* __restrict__ Bb,
    float* __restrict__ out)
{
  int row = blockIdx.x, t = threadIdx.x;
  float4 xa = ((const float4*)(P0 + (size_t)row*1024))[t];
  float4 xb = ((const float4*)(P1 + (size_t)row*1024))[t];
  float4 x;
  x.x = xa.x + xb.x; x.y = xa.y + xb.y; x.z = xa.z + xb.z; x.w = xa.w + xb.w;
  float s  = x.x + x.y + x.z + x.w;
  float s2 = x.x*x.x + x.y*x.y + x.z*x.z + x.w*x.w;
  #pragma unroll
  for (int o = 32; o > 0; o >>= 1){ s += __shfl_down(s, o); s2 += __shfl_down(s2, o); }
  __shared__ float red[8];
  int w = t >> 6;
  if ((t & 63) == 0){ red[w] = s; red[4 + w] = s2; }
  __syncthreads();
  float mu  = (red[0]+red[1]+red[2]+red[3]) * (1.0f/1024.0f);
  float var = (red[4]+red[5]+red[6]+red[7]) * (1.0f/1024.0f) - mu*mu;
  float rstd = rsqrtf(var + 1e-5f);
  float4 g = ((const float4*)G)[t];
  float4 b = ((const float4*)Bb)[t];
  float4 y;
  y.x = (x.x-mu)*rstd*g.x + b.x;
  y.y = (x.y-mu)*rstd*g.y + b.y;
  y.z = (x.z-mu)*rstd*g.z + b.z;
  y.w = (x.w-mu)*rstd*g.w + b.w;
  ((float4*)out)[(size_t)row*256 + t] = y;
}

// ---------------------------------------------------------------------------
// bt-GEMM mainloop, K-range parameterized (split-K support).
// ---------------------------------------------------------------------------
#define GEMM_MAINLOOP_K(A_, Bt_, tM_, tN_, KLO_, KHI_)                          \
  __shared__ __align__(16) short sA[128*64];                                    \
  __shared__ __align__(16) short sB[128*64];                                    \
  int t = threadIdx.x, w = t >> 6, lane = t & 63;                               \
  int wm = w & 1, wn = w >> 1, lm = lane & 15, q = lane >> 4;                   \
  int grow = lane >> 3;                                                         \
  int gchk = ((lane & 7) ^ grow) << 3;                                          \
  f32x4 acc[4][4] = {};                                                         \
  const unsigned short* Aw = A_ + (size_t)(tM_ + w*32 + grow)*1024 + gchk;      \
  const unsigned short* Bw = Bt_ + (size_t)(tN_ + w*32 + grow)*1024 + gchk;     \
  for (int kk = (KLO_); kk < (KHI_); kk += 64){                                 \
    __syncthreads();                                                            \
    gl2lds16(Aw + kk,            &sA[(w*32     )*64]);                          \
    gl2lds16(Aw + kk +  8*1024,  &sA[(w*32 +  8)*64]);                          \
    gl2lds16(Aw + kk + 16*1024,  &sA[(w*32 + 16)*64]);                          \
    gl2lds16(Aw + kk + 24*1024,  &sA[(w*32 + 24)*64]);                          \
    gl2lds16(Bw + kk,            &sB[(w*32     )*64]);                          \
    gl2lds16(Bw + kk +  8*1024,  &sB[(w*32 +  8)*64]);                          \
    gl2lds16(Bw + kk + 16*1024,  &sB[(w*32 + 16)*64]);                          \
    gl2lds16(Bw + kk + 24*1024,  &sB[(w*32 + 24)*64]);                          \
    __syncthreads();                                                            \
    bf16x8 af[4][2], bfr[4][2];                                                 \
    _Pragma("unroll")                                                           \
    for (int i = 0; i < 4; ++i){                                                \
      int ra = wm*64 + i*16 + lm, rb = wn*64 + i*16 + lm;                       \
      _Pragma("unroll")                                                         \
      for (int hh = 0; hh < 2; ++hh){                                           \
        int sw = ((hh*4 + q) ^ (lm & 7)) << 3;                                  \
        af[i][hh]  = *(const bf16x8*)(&sA[ra*64 + sw]);                         \
        bfr[i][hh] = *(const bf16x8*)(&sB[rb*64 + sw]);                         \
      }                                                                         \
    }                                                                           \
    _Pragma("unroll")                                                           \
    for (int hh = 0; hh < 2; ++hh)                                              \
      _Pragma("unroll")                                                         \
      for (int i = 0; i < 4; ++i)                                               \
        _Pragma("unroll")                                                       \
        for (int j = 0; j < 4; ++j)                                             \
          acc[i][j] = __builtin_amdgcn_mfma_f32_16x16x32_bf16(af[i][hh], bfr[j][hh], acc[i][j], 0, 0, 0); \
  }

#define GEMM_MAINLOOP(A_, Bt_, tM_, tN_) GEMM_MAINLOOP_K(A_, Bt_, tM_, tN_, 0, 1024)

// QKV GEMM (1D grid 768). XCD swizzle: 8 M-tiles x 12 N-tiles per XCD.
__global__ __launch_bounds__(256) void gemm_qkv_kernel(
    const unsigned short* __restrict__ A, const unsigned short* __restrict__ Bt,
    unsigned short* __restrict__ Qb, unsigned short* __restrict__ Kb,
    unsigned short* __restrict__ VtG)
{
  int id = blockIdx.x;
  int xcd = id & 7, r = id >> 3;          // r in [0,96)
  int tM = ((xcd >> 1)*8 + (r & 7)) * 128;
  int tN = ((xcd & 1)*12 + (r >> 3)) * 128;   // [0,24) -> Q/K/V regions
  GEMM_MAINLOOP(A, Bt, tM, tN)
  if (tN < 1024){                 // Q region
    #pragma unroll
    for (int i = 0; i < 4; ++i){
      int R0 = tM + wm*64 + i*16 + q*4;
      int b = R0 >> 11, n = R0 & 2047;
      #pragma unroll
      for (int j = 0; j < 4; ++j){
        int Cg = tN + wn*64 + j*16 + lm;
        int h = Cg >> 6, d = Cg & 63;
        size_t base = ((((size_t)(b*16 + h) << 11) | n) << 6) + d;
        #pragma unroll
        for (int rr = 0; rr < 4; ++rr)
          Qb[base + (size_t)rr*64] = f2b(acc[i][j][rr] * QSCALE);
      }
    }
  } else if (tN < 2048){          // K region
    #pragma unroll
    for (int i = 0; i < 4; ++i){
      int R0 = tM + wm*64 + i*16 + q*4;
      int b = R0 >> 11, n = R0 & 2047;
      #pragma unroll
      for (int j = 0; j < 4; ++j){
        int c2 = tN - 1024 + wn*64 + j*16 + lm;
        int h = c2 >> 6, d = c2 & 63;
        size_t base = ((((size_t)(b*16 + h) << 11) | n) << 6) + d;
        #pragma unroll
        for (int rr = 0; rr < 4; ++rr)
          Kb[base + (size_t)rr*64] = f2b(acc[i][j][rr]);
      }
    }
  } else {                        // V region -> transposed, packed 8B stores
    #pragma unroll
    for (int i = 0; i < 4; ++i){
      int R0 = tM + wm*64 + i*16 + q*4;
      int b = R0 >> 11, n = R0 & 2047;
      #pragma unroll
      for (int j = 0; j < 4; ++j){
        int c2 = tN - 2048 + wn*64 + j*16 + lm;
        int h = c2 >> 6, d = c2 & 63;
        ushort4 u;
        u.x = f2b(acc[i][j][0]); u.y = f2b(acc[i][j][1]);
        u.z = f2b(acc[i][j][2]); u.w = f2b(acc[i][j][3]);
        *(ushort4*)(VtG + ((size_t)(b*16 + h)*64 + d)*2048 + n) = u;
      }
    }
  }
}

// Out-proj GEMM, split-K 2-way (kept from R8: non-attn time 198.5 -> 193.9).
__global__ __launch_bounds__(256) void gemm_out_kernel(
    const unsigned short* __restrict__ A, const unsigned short* __restrict__ Bt,
    float* __restrict__ C0, float* __restrict__ C1)
{
  int id = blockIdx.x;
  int xcd = id & 7, r = id >> 3;          // r in [0,64)
  int ks = r & 1;                          // K slice
  int r2 = r >> 1;                         // [0,32)
  int tM = ((r2 & 3)*8 + xcd) * 128;
  int tN = (r2 >> 2) * 128;                // [0,8)
  float* C = ks ? C1 : C0;
  GEMM_MAINLOOP_K(A, Bt, tM, tN, ks*512, ks*512 + 512)
  #pragma unroll
  for (int i = 0; i < 4; ++i){
    int R0 = tM + wm*64 + i*16 + q*4;
    #pragma unroll
    for (int j = 0; j < 4; ++j){
      int Cg = tN + wn*64 + j*16 + lm;
      #pragma unroll
      for (int rr = 0; rr < 4; ++rr)
        C[(size_t)(R0 + rr)*1024 + Cg] = acc[i][j][rr];
    }
  }
}

// ---------------------------------------------------------------------------
// Flash attention — R10 geometry under the 85-VGPR line (third submission of
// the R11 kernel; R11 = "container failed twice", R12 = explicit
// GPUAcquisitionTimeout — both infra, kernel never measured).
// OCCUPANCY LAW (fit to 9 measured rounds): resident waves/SIMD =
// floor(256 / VGPR_Count), then capped by LDS and grid. R10 failed at
// VGPR=92 (floor(256/92)=2 -> 8 waves/CU) even with 40KB LDS slack.
// Fix: __launch_bounds__(256,3) (compiler cap = 256/3 = 85) + shrink the
// dominant live range (kf[4][2]=16 regs held across QK^T -> per-st kf0/kf1,
// 2 regs). R8's unswizzled sibling measured 84 -> 85 is reachable.
// Target: VGPR<=85 -> 3 waves/SIMD -> 3 blocks/CU = 12 waves/CU.
// Grid = 32 bh * 32 chunks = 1024 (xcd-swizzled), 64 queries/block,
// 4 waves in 2 pairs (18/17 key tiles), additive no-max log2-softmax.
// LDS carve (40960 B): [0,16384) K | [16384,32768) Vt | [32768,40960) P.
// K/V: 64x64 shorts, granule g at g^(row&7) (write rsw=r0&7, read esw=lm&7).
// Merge overlay [0,18432) after final barrier (K/Vt dead).
// KILL: occupancy <=19% or WRITE_SIZE>20MB -> revert to R9 128-query form.
// ---------------------------------------------------------------------------
__global__ __launch_bounds__(256, 3) void attn_kernel(
    const unsigned short* __restrict__ Qb, const unsigned short* __restrict__ Kb,
    const unsigned short* __restrict__ VtG, const unsigned short* __restrict__ kext,
    const unsigned short* __restrict__ vext_t, unsigned short* __restrict__ Ob)
{
  __shared__ __align__(16) char smem[40960];
  int id = blockIdx.x;
  int xcd = id & 7, slot = id >> 3;              // slot in [0,128)
  int bh = xcd*4 + (slot >> 5);                  // 4 bh per XCD for L2 locality
  int q64 = slot & 31;                           // 64-query chunk
  int b = bh >> 4, h = bh & 15;
  int t = threadIdx.x, w = t >> 6, lane = t & 63;
  int p = w >> 1, lw = w & 1;
  int lm = lane & 15, q = lane >> 4;
  int esw = lm & 7;                              // read-side swizzle key

  short* myK = (short*)(smem + p*8192);
  short* myV = (short*)(smem + 16384 + p*8192);
  short* pw  = (short*)(smem + 32768 + w*2048);

  const unsigned short* Qbase = Qb + ((size_t)bh*2048 + q64*64 + lw*32)*64;
  bf16x8 qf[2][2];
  #pragma unroll
  for (int qq = 0; qq < 2; ++qq){
    qf[qq][0] = *(const bf16x8*)(Qbase + (size_t)(qq*16 + lm)*64 + q*8);
    qf[qq][1] = *(const bf16x8*)(Qbase + (size_t)(qq*16 + lm)*64 + q*8 + 32);
  }

  f32x4 o[4][2] = {};                            // [ds][qq]
  float l_i[2] = {0.f, 0.f};

  // staging within the pair: 128 threads, row r0, 32-short half c0
  int pt = t & 127;
  int r0 = pt >> 1, c0 = (pt & 1) << 5;
  int rsw = r0 & 7;                              // write-side swizzle key
  const int t0 = p ? 18 : 0;
  const int t1 = p ? 35 : 18;

  u32x4 kr[4], vr[4];
  {
    const unsigned short* kp = Kb + ((size_t)bh*2048 + t0*64 + r0)*64 + c0;
    const unsigned short* vp = VtG + ((size_t)bh*64 + r0)*2048 + t0*64 + c0;
    #pragma unroll
    for (int jj = 0; jj < 4; ++jj){
      kr[jj] = *(const u32x4*)(kp + 8*jj);
      vr[jj] = *(const u32x4*)(vp + 8*jj);
    }
  }

  for (int it = 0; it < 18; ++it){
    int tile = t0 + it;
    bool valid = tile < t1;
    __syncthreads();
    if (valid){
      #pragma unroll
      for (int jj = 0; jj < 4; ++jj){
        int gsw = ((((pt & 1) << 2) | jj) ^ rsw) << 3;
        *(u32x4*)(&myK[r0*64 + gsw]) = kr[jj];
        *(u32x4*)(&myV[r0*64 + gsw]) = vr[jj];
      }
    }
    __syncthreads();

    int nt = tile + 1;
    if (nt < t1){                                // prefetch next tile
      bool ext = nt >= 32;
      int kb = ext ? (nt - 32)*64 : nt*64;
      const unsigned short* kp = ext ? (kext + ((size_t)b*192 + kb + r0)*64 + c0)
                                     : (Kb + ((size_t)bh*2048 + kb + r0)*64 + c0);
      const unsigned short* vp = ext ? (vext_t + ((size_t)b*64 + r0)*192 + kb + c0)
                                     : (VtG + ((size_t)bh*64 + r0)*2048 + kb + c0);
      #pragma unroll
      for (int jj = 0; jj < 4; ++jj){
        kr[jj] = *(const u32x4*)(kp + 8*jj);
        vr[jj] = *(const u32x4*)(vp + 8*jj);
      }
    }
    if (!valid) continue;                        // barriers already passed

    // QK^T: kf loaded per-st (2 live regs instead of 16)
    f32x4 s[2][4];
    #pragma unroll
    for (int st = 0; st < 4; ++st){
      bf16x8 kf0 = *(const bf16x8*)(&myK[(st*16 + lm)*64 + ((q       ^ esw) << 3)]);
      bf16x8 kf1 = *(const bf16x8*)(&myK[(st*16 + lm)*64 + (((4 + q) ^ esw) << 3)]);
      #pragma unroll
      for (int qh = 0; qh < 2; ++qh){
        f32x4 z = {};
        z = __builtin_amdgcn_mfma_f32_16x16x32_bf16(kf0, qf[qh][0], z, 0, 0, 0);
        s[qh][st] = __builtin_amdgcn_mfma_f32_16x16x32_bf16(kf1, qf[qh][1], z, 0, 0, 0);
      }
    }
    if (tile == 34){                             // keys 128..191: only 128 valid
      #pragma unroll
      for (int qh = 0; qh < 2; ++qh)
        #pragma unroll
        for (int st = 0; st < 4; ++st)
          #pragma unroll
          for (int rr = 0; rr < 4; ++rr){
            int key = 128 + st*16 + q*4 + rr;
            if (key >= 129) s[qh][st][rr] = -1e30f;
          }
    }
    bf16x8 pb[2][2];
    #pragma unroll
    for (int qh = 0; qh < 2; ++qh){              // per-qh: exp, pack->pw, read
      float sm = 0.f;
      #pragma unroll
      for (int st = 0; st < 4; ++st)
        #pragma unroll
        for (int rr = 0; rr < 4; ++rr){
          float pv = __builtin_amdgcn_exp2f(s[qh][st][rr]);
          s[qh][st][rr] = pv; sm += pv;
        }
      l_i[qh] += sm;
      #pragma unroll
      for (int st = 0; st < 4; ++st){
        u32x2 pkd;
        pkd[0] = pk2(s[qh][st][0], s[qh][st][1]);
        pkd[1] = pk2(s[qh][st][2], s[qh][st][3]);
        int gsw = ((((st << 1) | (q >> 1)) ^ esw) << 3) + ((q & 1) << 2);
        *(u32x2*)(&pw[lm*64 + gsw]) = pkd;
      }
      // read back (own-wave region, in-order DS pipe -> no barrier)
      bf16x4 a0 = *(const bf16x4*)(&pw[lm*64 + ((q       ^ esw) << 3)]);
      bf16x4 a1 = *(const bf16x4*)(&pw[lm*64 + ((q       ^ esw) << 3) + 4]);
      bf16x4 a2 = *(const bf16x4*)(&pw[lm*64 + (((4 + q) ^ esw) << 3)]);
      bf16x4 a3 = *(const bf16x4*)(&pw[lm*64 + (((4 + q) ^ esw) << 3) + 4]);
      pb[qh][0] = __builtin_shufflevector(a0, a1, 0,1,2,3,4,5,6,7);
      pb[qh][1] = __builtin_shufflevector(a2, a3, 0,1,2,3,4,5,6,7);
    }
    #pragma unroll
    for (int ds = 0; ds < 4; ++ds){
      bf16x8 af0 = *(const bf16x8*)(&myV[(ds*16 + lm)*64 + ((q       ^ esw) << 3)]);
      bf16x8 af1 = *(const bf16x8*)(&myV[(ds*16 + lm)*64 + (((4 + q) ^ esw) << 3)]);
      #pragma unroll
      for (int qh = 0; qh < 2; ++qh){
        o[ds][qh] = __builtin_amdgcn_mfma_f32_16x16x32_bf16(af0, pb[qh][0], o[ds][qh], 0, 0, 0);
        o[ds][qh] = __builtin_amdgcn_mfma_f32_16x16x32_bf16(af1, pb[qh][1], o[ds][qh], 0, 0, 0);
      }
    }
  }

  // ---- merge the two key-halves (additive: no rescale needed) ----
  // overlay at smem offset 0: 2 lw-slots x 64 lanes x 36 floats = 18432 B
  // (K region dead; spills into Vt region, also dead past this barrier)
  float* mb = (float*)smem;
  float* reg = mb + lw*2304 + lane*36;
  __syncthreads();                               // all KV/P reads done
  if (p == 1){
    #pragma unroll
    for (int ds = 0; ds < 4; ++ds)
      #pragma unroll
      for (int qq = 0; qq < 2; ++qq)
        *(f32x4*)(reg + (ds*2 + qq)*4) = o[ds][qq];
    #pragma unroll
    for (int qq = 0; qq < 2; ++qq) reg[32 + qq] = l_i[qq];
  }
  __syncthreads();
  if (p == 0){
    #pragma unroll
    for (int qq = 0; qq < 2; ++qq){
      #pragma unroll
      for (int ds = 0; ds < 4; ++ds){
        f32x4 ov = *(const f32x4*)(reg + (ds*2 + qq)*4);
        o[ds][qq] += ov;
      }
      float l = l_i[qq] + reg[32 + qq];
      l += __shfl_xor(l, 16);
      l += __shfl_xor(l, 32);
      float inv = 1.0f / l;
      int n = q64*64 + lw*32 + qq*16 + lm;
      size_t base = ((size_t)b*2048 + n)*1024 + h*64 + q*4;
      #pragma unroll
      for (int ds = 0; ds < 4; ++ds){
        ushort4 u;
        u.x = f2b(o[ds][qq][0] * inv); u.y = f2b(o[ds][qq][1] * inv);
        u.z = f2b(o[ds][qq][2] * inv); u.w = f2b(o[ds][qq][3] * inv);
        *(ushort4*)(Ob + base + ds*16) = u;
      }
    }
  }
}

// ---------------------------------------------------------------------------
extern "C" void kernel_launch(void* const* d_in, const int* in_sizes, int n_in,
                              void* d_out, int out_size, void* d_ws, size_t ws_size,
                              hipStream_t stream)
{
  const float* x       = (const float*)d_in[0];
  const float* c_emb   = (const float*)d_in[1];
  const float* ln_g    = (const float*)d_in[2];
  const float* ln_b    = (const float*)d_in[3];
  const float* ctx_g   = (const float*)d_in[4];
  const float* ctx_b   = (const float*)d_in[5];
  const float* W_ctx   = (const float*)d_in[6];
  const float* b_ctx   = (const float*)d_in[7];
  const float* W_q     = (const float*)d_in[8];
  const float* W_kv    = (const float*)d_in[9];
  const float* null_kv = (const float*)d_in[10];
  const float* W_out   = (const float*)d_in[11];
  const float* oln_g   = (const float*)d_in[12];
  const float* oln_b   = (const float*)d_in[13];
  float* out = (float*)d_out;

  char* p = (char*)d_ws;
  unsigned short* xn     = (unsigned short*)p; p += (size_t)4096*1024*2;
  unsigned short* Wqkv_t = (unsigned short*)p; p += (size_t)3072*1024*2;
  unsigned short* Wout_t = (unsigned short*)p; p += (size_t)1024*1024*2;
  unsigned short* Qb     = (unsigned short*)p; p += (size_t)32*2048*64*2;
  unsigned short* Kb     = (unsigned short*)p; p += (size_t)32*2048*64*2;
  unsigned short* VtG    = (unsigned short*)p; p += (size_t)32*64*2048*2;
  unsigned short* kext   = (unsigned short*)p; p += (size_t)2*192*64*2;
  unsigned short* vext_t = (unsigned short*)p; p += (size_t)2*64*192*2;
  unsigned short* aout   = (unsigned short*)p; p += (size_t)4096*1024*2;
  float*          ptmp   = (float*)p;          p += (size_t)4096*1024*4;
  // split-K partial #2 overlays Qb+Kb (16 MB, dead after attn completes)
  float*          ptmp1  = (float*)Qb;

  prologue_kernel<<<5376, 256, 0, stream>>>(
      W_q, W_kv, W_out, Wqkv_t, Wout_t,
      x, ln_g, ln_b, xn,
      c_emb, ctx_g, ctx_b, W_ctx, b_ctx, null_kv, kext, vext_t);
  gemm_qkv_kernel<<<768, 256, 0, stream>>>(xn, Wqkv_t, Qb, Kb, VtG);
  attn_kernel<<<1024, 256, 0, stream>>>(Qb, Kb, VtG, kext, vext_t, aout);
  gemm_out_kernel<<<512, 256, 0, stream>>>(aout, Wout_t, ptmp, ptmp1);
  ln1024f_kernel<<<4096, 256, 0, stream>>>(ptmp, ptmp1, oln_g, oln_b, out);
}

// Round 14
// 260.582 us; speedup vs baseline: 1.0255x; 1.0116x over previous
//
#include <hip/hip_runtime.h>
#include <cstdint>
#include <cstddef>

typedef __attribute__((ext_vector_type(8))) short bf16x8;
typedef __attribute__((ext_vector_type(4))) short bf16x4;
typedef __attribute__((ext_vector_type(4))) float f32x4;
typedef __attribute__((ext_vector_type(4))) unsigned int u32x4;
typedef __attribute__((ext_vector_type(2))) unsigned int u32x2;

__device__ inline unsigned short f2b(float f){
  unsigned int u = __float_as_uint(f);
  u += 0x7fffu + ((u >> 16) & 1u);
  return (unsigned short)(u >> 16);
}
// pack two fp32 -> bf16 pair via v_perm (probs >= 0, round-half-up)
__device__ inline unsigned int pk2(float a, float b){
  unsigned int ua = __float_as_uint(a) + 0x8000u;
  unsigned int ub = __float_as_uint(b) + 0x8000u;
  return __builtin_amdgcn_perm(ub, ua, 0x07060302u);
}
// async global->LDS, 16B/lane; LDS dest = wave-uniform base + lane*16
__device__ inline void gl2lds16(const void* g, void* l){
  __builtin_amdgcn_global_load_lds(
      (const __attribute__((address_space(1))) unsigned int*)g,
      (__attribute__((address_space(3))) unsigned int*)l, 16, 0, 0);
}

#define QSCALE 0.18033688011112042f   // 0.125 * log2(e): softmax in log2 domain

// ---------------------------------------------------------------------------
// Fused prologue (unchanged from R7): wcvt | ln->bf16 | ctx in one dispatch.
// ---------------------------------------------------------------------------
__global__ __launch_bounds__(256) void prologue_kernel(
    const float* __restrict__ Wq, const float* __restrict__ Wkv,
    const float* __restrict__ Wout,
    unsigned short* __restrict__ Wqkv_t, unsigned short* __restrict__ Wout_t,
    const float* __restrict__ X, const float* __restrict__ G,
    const float* __restrict__ Bb, unsigned short* __restrict__ xn,
    const float* __restrict__ Cemb, const float* __restrict__ cG,
    const float* __restrict__ cBb, const float* __restrict__ Wctx,
    const float* __restrict__ bctx, const float* __restrict__ nullkv,
    unsigned short* __restrict__ kext, unsigned short* __restrict__ vext_t)
{
  __shared__ __align__(16) char fsm[9216];
  int bid = blockIdx.x;
  int t = threadIdx.x;

  if (bid < 1024){
    short* tile = (short*)fsm;
    int cg0 = (bid & 63) * 64;
    int kt  = (bid >> 6) * 64;
    const float* src; int ld; int col0; unsigned short* dst; int drow0;
    if (cg0 < 1024)      { src = Wq;   ld = 1024; col0 = cg0;        dst = Wqkv_t; drow0 = cg0; }
    else if (cg0 < 3072) { src = Wkv;  ld = 2048; col0 = cg0 - 1024; dst = Wqkv_t; drow0 = cg0; }
    else                 { src = Wout; ld = 1024; col0 = cg0 - 3072; dst = Wout_t; drow0 = cg0 - 3072; }
    #pragma unroll
    for (int i = 0; i < 16; ++i){
      int lin = t + 256*i;
      int k = lin >> 6, c = lin & 63;
      tile[k*72 + c] = (short)f2b(src[(size_t)(kt + k)*ld + col0 + c]);
    }
    __syncthreads();
    #pragma unroll
    for (int i = 0; i < 16; ++i){
      int lin = t + 256*i;
      int c = lin >> 6, k = lin & 63;
      dst[(size_t)(drow0 + c)*1024 + kt + k] = (unsigned short)tile[k*72 + c];
    }
  } else if (bid < 5120){
    int row = bid - 1024;
    float* red = (float*)fsm;
    float4 x = ((const float4*)(X + (size_t)row*1024))[t];
    float s  = x.x + x.y + x.z + x.w;
    float s2 = x.x*x.x + x.y*x.y + x.z*x.z + x.w*x.w;
    #pragma unroll
    for (int o = 32; o > 0; o >>= 1){ s += __shfl_down(s, o); s2 += __shfl_down(s2, o); }
    int w = t >> 6;
    if ((t & 63) == 0){ red[w] = s; red[4 + w] = s2; }
    __syncthreads();
    float mu  = (red[0]+red[1]+red[2]+red[3]) * (1.0f/1024.0f);
    float var = (red[4]+red[5]+red[6]+red[7]) * (1.0f/1024.0f) - mu*mu;
    float rstd = rsqrtf(var + 1e-5f);
    float4 g = ((const float4*)G)[t];
    float4 b = ((const float4*)Bb)[t];
    ushort4 u;
    u.x = f2b((x.x-mu)*rstd*g.x + b.x);
    u.y = f2b((x.y-mu)*rstd*g.y + b.y);
    u.z = f2b((x.z-mu)*rstd*g.z + b.z);
    u.w = f2b((x.w-mu)*rstd*g.w + b.w);
    ((ushort4*)xn)[(size_t)row*256 + t] = u;
  } else {
    int row = bid - 5120;            // 0..255 (b*128 + m)
    int b = row >> 7, m = row & 127;
    bool act = t < 128;
    float* red  = (float*)fsm;
    float* xns  = (float*)(fsm + 16);
    if (act && row < 128){
      int b2 = row >> 6, fr = row & 63;
      int frow = (fr == 0) ? 0 : (128 + fr);
      if (t < 64){
        kext[((size_t)b2*192 + frow)*64 + t] = (frow == 0) ? f2b(nullkv[t]) : (unsigned short)0;
      } else {
        int d = t - 64;
        vext_t[((size_t)b2*64 + d)*192 + frow] = (frow == 0) ? f2b(nullkv[64 + d]) : (unsigned short)0;
      }
    }
    const float* xr = Cemb + (size_t)row*768;
    float v[6]; float s = 0.f, s2 = 0.f;
    if (act){
      #pragma unroll
      for (int j = 0; j < 6; ++j){ float xv = xr[t + 128*j]; v[j] = xv; s += xv; s2 += xv*xv; }
      #pragma unroll
      for (int o = 32; o > 0; o >>= 1){ s += __shfl_down(s, o); s2 += __shfl_down(s2, o); }
      int w = t >> 6;
      if ((t & 63) == 0){ red[w] = s; red[2 + w] = s2; }
    }
    __syncthreads();
    if (act){
      float mu  = (red[0]+red[1]) * (1.0f/768.0f);
      float var = (red[2]+red[3]) * (1.0f/768.0f) - mu*mu;
      float rstd = rsqrtf(var + 1e-5f);
      #pragma unroll
      for (int j = 0; j < 6; ++j){ int c = t + 128*j; xns[c] = (v[j]-mu)*rstd*cG[c] + cBb[c]; }
    }
    __syncthreads();
    if (act){
      float acc = bctx[t];
      #pragma unroll 8
      for (int j = 0; j < 768; ++j) acc += xns[j] * Wctx[j*128 + t];
      unsigned short hv = f2b(acc);
      if (t < 64) kext[((size_t)b*192 + 1 + m)*64 + t] = hv;
      else        vext_t[((size_t)b*64 + (t - 64))*192 + 1 + m] = hv;
    }
  }
}

// ---------------------------------------------------------------------------
// Final LayerNorm over 1024 cols; input = P0 + P1 (split-K partial sums).
// ---------------------------------------------------------------------------
__global__ __launch_bounds__(256) void ln1024f_kernel(
    const float* __restrict__ P0, const float* __restrict__ P1,
    const float* __restrict__ G, const float* __restrict__ Bb,
    float* __restrict__ out)
{
  int row = blockIdx.x, t = threadIdx.x;
  float4 xa = ((const float4*)(P0 + (size_t)row*1024))[t];
  float4 xb = ((const float4*)(P1 + (size_t)row*1024))[t];
  float4 x;
  x.x = xa.x + xb.x; x.y = xa.y + xb.y; x.z = xa.z + xb.z; x.w = xa.w + xb.w;
  float s  = x.x + x.y + x.z + x.w;
  float s2 = x.x*x.x + x.y*x.y + x.z*x.z + x.w*x.w;
  #pragma unroll
  for (int o = 32; o > 0; o >>= 1){ s += __shfl_down(s, o); s2 += __shfl_down(s2, o); }
  __shared__ float red[8];
  int w = t >> 6;
  if ((t & 63) == 0){ red[w] = s; red[4 + w] = s2; }
  __syncthreads();
  float mu  = (red[0]+red[1]+red[2]+red[3]) * (1.0f/1024.0f);
  float var = (red[4]+red[5]+red[6]+red[7]) * (1.0f/1024.0f) - mu*mu;
  float rstd = rsqrtf(var + 1e-5f);
  float4 g = ((const float4*)G)[t];
  float4 b = ((const float4*)Bb)[t];
  float4 y;
  y.x = (x.x-mu)*rstd*g.x + b.x;
  y.y = (x.y-mu)*rstd*g.y + b.y;
  y.z = (x.z-mu)*rstd*g.z + b.z;
  y.w = (x.w-mu)*rstd*g.w + b.w;
  ((float4*)out)[(size_t)row*256 + t] = y;
}

// ---------------------------------------------------------------------------
// bt-GEMM mainloop, K-range parameterized (split-K support).
// ---------------------------------------------------------------------------
#define GEMM_MAINLOOP_K(A_, Bt_, tM_, tN_, KLO_, KHI_)                          \
  __shared__ __align__(16) short sA[128*64];                                    \
  __shared__ __align__(16) short sB[128*64];                                    \
  int t = threadIdx.x, w = t >> 6, lane = t & 63;                               \
  int wm = w & 1, wn = w >> 1, lm = lane & 15, q = lane >> 4;                   \
  int grow = lane >> 3;                                                         \
  int gchk = ((lane & 7) ^ grow) << 3;                                          \
  f32x4 acc[4][4] = {};                                                         \
  const unsigned short* Aw = A_ + (size_t)(tM_ + w*32 + grow)*1024 + gchk;      \
  const unsigned short* Bw = Bt_ + (size_t)(tN_ + w*32 + grow)*1024 + gchk;     \
  for (int kk = (KLO_); kk < (KHI_); kk += 64){                                 \
    __syncthreads();                                                            \
    gl2lds16(Aw + kk,            &sA[(w*32     )*64]);                          \
    gl2lds16(Aw + kk +  8*1024,  &sA[(w*32 +  8)*64]);                          \
    gl2lds16(Aw + kk + 16*1024,  &sA[(w*32 + 16)*64]);                          \
    gl2lds16(Aw + kk + 24*1024,  &sA[(w*32 + 24)*64]);                          \
    gl2lds16(Bw + kk,            &sB[(w*32     )*64]);                          \
    gl2lds16(Bw + kk +  8*1024,  &sB[(w*32 +  8)*64]);                          \
    gl2lds16(Bw + kk + 16*1024,  &sB[(w*32 + 16)*64]);                          \
    gl2lds16(Bw + kk + 24*1024,  &sB[(w*32 + 24)*64]);                          \
    __syncthreads();                                                            \
    bf16x8 af[4][2], bfr[4][2];                                                 \
    _Pragma("unroll")                                                           \
    for (int i = 0; i < 4; ++i){                                                \
      int ra = wm*64 + i*16 + lm, rb = wn*64 + i*16 + lm;                       \
      _Pragma("unroll")                                                         \
      for (int hh = 0; hh < 2; ++hh){                                           \
        int sw = ((hh*4 + q) ^ (lm & 7)) << 3;                                  \
        af[i][hh]  = *(const bf16x8*)(&sA[ra*64 + sw]);                         \
        bfr[i][hh] = *(const bf16x8*)(&sB[rb*64 + sw]);                         \
      }                                                                         \
    }                                                                           \
    _Pragma("unroll")                                                           \
    for (int hh = 0; hh < 2; ++hh)                                              \
      _Pragma("unroll")                                                         \
      for (int i = 0; i < 4; ++i)                                               \
        _Pragma("unroll")                                                       \
        for (int j = 0; j < 4; ++j)                                             \
          acc[i][j] = __builtin_amdgcn_mfma_f32_16x16x32_bf16(af[i][hh], bfr[j][hh], acc[i][j], 0, 0, 0); \
  }

#define GEMM_MAINLOOP(A_, Bt_, tM_, tN_) GEMM_MAINLOOP_K(A_, Bt_, tM_, tN_, 0, 1024)

// QKV GEMM (1D grid 768). XCD swizzle: 8 M-tiles x 12 N-tiles per XCD.
__global__ __launch_bounds__(256) void gemm_qkv_kernel(
    const unsigned short* __restrict__ A, const unsigned short* __restrict__ Bt,
    unsigned short* __restrict__ Qb, unsigned short* __restrict__ Kb,
    unsigned short* __restrict__ VtG)
{
  int id = blockIdx.x;
  int xcd = id & 7, r = id >> 3;          // r in [0,96)
  int tM = ((xcd >> 1)*8 + (r & 7)) * 128;
  int tN = ((xcd & 1)*12 + (r >> 3)) * 128;   // [0,24) -> Q/K/V regions
  GEMM_MAINLOOP(A, Bt, tM, tN)
  if (tN < 1024){                 // Q region
    #pragma unroll
    for (int i = 0; i < 4; ++i){
      int R0 = tM + wm*64 + i*16 + q*4;
      int b = R0 >> 11, n = R0 & 2047;
      #pragma unroll
      for (int j = 0; j < 4; ++j){
        int Cg = tN + wn*64 + j*16 + lm;
        int h = Cg >> 6, d = Cg & 63;
        size_t base = ((((size_t)(b*16 + h) << 11) | n) << 6) + d;
        #pragma unroll
        for (int rr = 0; rr < 4; ++rr)
          Qb[base + (size_t)rr*64] = f2b(acc[i][j][rr] * QSCALE);
      }
    }
  } else if (tN < 2048){          // K region
    #pragma unroll
    for (int i = 0; i < 4; ++i){
      int R0 = tM + wm*64 + i*16 + q*4;
      int b = R0 >> 11, n = R0 & 2047;
      #pragma unroll
      for (int j = 0; j < 4; ++j){
        int c2 = tN - 1024 + wn*64 + j*16 + lm;
        int h = c2 >> 6, d = c2 & 63;
        size_t base = ((((size_t)(b*16 + h) << 11) | n) << 6) + d;
        #pragma unroll
        for (int rr = 0; rr < 4; ++rr)
          Kb[base + (size_t)rr*64] = f2b(acc[i][j][rr]);
      }
    }
  } else {                        // V region -> transposed, packed 8B stores
    #pragma unroll
    for (int i = 0; i < 4; ++i){
      int R0 = tM + wm*64 + i*16 + q*4;
      int b = R0 >> 11, n = R0 & 2047;
      #pragma unroll
      for (int j = 0; j < 4; ++j){
        int c2 = tN - 2048 + wn*64 + j*16 + lm;
        int h = c2 >> 6, d = c2 & 63;
        ushort4 u;
        u.x = f2b(acc[i][j][0]); u.y = f2b(acc[i][j][1]);
        u.z = f2b(acc[i][j][2]); u.w = f2b(acc[i][j][3]);
        *(ushort4*)(VtG + ((size_t)(b*16 + h)*64 + d)*2048 + n) = u;
      }
    }
  }
}

// Out-proj GEMM, split-K 2-way (kept from R8: non-attn time 198.5 -> 193.9).
__global__ __launch_bounds__(256) void gemm_out_kernel(
    const unsigned short* __restrict__ A, const unsigned short* __restrict__ Bt,
    float* __restrict__ C0, float* __restrict__ C1)
{
  int id = blockIdx.x;
  int xcd = id & 7, r = id >> 3;          // r in [0,64)
  int ks = r & 1;                          // K slice
  int r2 = r >> 1;                         // [0,32)
  int tM = ((r2 & 3)*8 + xcd) * 128;
  int tN = (r2 >> 2) * 128;                // [0,8)
  float* C = ks ? C1 : C0;
  GEMM_MAINLOOP_K(A, Bt, tM, tN, ks*512, ks*512 + 512)
  #pragma unroll
  for (int i = 0; i < 4; ++i){
    int R0 = tM + wm*64 + i*16 + q*4;
    #pragma unroll
    for (int j = 0; j < 4; ++j){
      int Cg = tN + wn*64 + j*16 + lm;
      #pragma unroll
      for (int rr = 0; rr < 4; ++rr)
        C[(size_t)(R0 + rr)*1024 + Cg] = acc[i][j][rr];
    }
  }
}

// ---------------------------------------------------------------------------
// Flash attention — R9's proven 128-query geometry (65.1 us banked; R13's
// 64-query/3-block variant measured 71.1 -> 64-query geometry is dead at
// BOTH occupancies), plus ONE contained change: double-buffered K/V staging
// -> ONE barrier per key tile instead of two.
// Race-freedom: in iter i the staging write targets buf[d^1], whose last
// readers (iter i-1) finished before barrier(i-1); the write happens after
// barrier(i-1); barrier(i) publishes it before iter i+1's reads.
// Iter order: write-next(from kr/vr) -> issue loads(tile+2) -> compute(cur)
// -> barrier.  35 tiles: ~17 barriers saved per block.
// LDS carve (73728 B, 2 blocks/CU: 147456 <= 163840, 16KB slack):
//   [0,32768)      K bufs: d*16384 + p*8192
//   [32768,65536)  Vt bufs: 32768 + d*16384 + p*8192
//   [65536,73728)  P scratch (wave w at 65536 + w*2048)
// K/V rows: 64x64 shorts, granule g at g^(row&7) (write rsw, read esw) — R9.
// Merge overlay [0,34816) after final barrier (K bufs + start of V, dead).
// KILL: attn >= 65.5us or correctness -> revert to plain R9 attn.
// ---------------------------------------------------------------------------
__global__ __launch_bounds__(256, 2) void attn_kernel(
    const unsigned short* __restrict__ Qb, const unsigned short* __restrict__ Kb,
    const unsigned short* __restrict__ VtG, const unsigned short* __restrict__ kext,
    const unsigned short* __restrict__ vext_t, unsigned short* __restrict__ Ob)
{
  __shared__ __align__(16) char smem[73728];
  int id = blockIdx.x;
  int xcd = id & 7, slot = id >> 3;              // 4 bh per XCD for L2 locality
  int bh = xcd*4 + (slot >> 4);
  int qt = slot & 15;
  int b = bh >> 4, h = bh & 15;
  int t = threadIdx.x, w = t >> 6, lane = t & 63;
  int p = w >> 1, lw = w & 1;
  int lm = lane & 15, q = lane >> 4;
  int esw = lm & 7;                              // read-side swizzle key

  short* pw = (short*)(smem + 65536 + w*2048);

  const unsigned short* Qbase = Qb + ((size_t)bh*2048 + qt*128 + lw*64)*64;
  bf16x8 qf[4][2];
  #pragma unroll
  for (int qq = 0; qq < 4; ++qq){
    qf[qq][0] = *(const bf16x8*)(Qbase + (size_t)(qq*16 + lm)*64 + q*8);
    qf[qq][1] = *(const bf16x8*)(Qbase + (size_t)(qq*16 + lm)*64 + q*8 + 32);
  }

  f32x4 o[4][4] = {};                            // [ds][qq]
  float l_i[4] = {0.f, 0.f, 0.f, 0.f};

  // staging within the pair: 128 threads, row r0, 32-short half c0
  int pt = t & 127;
  int r0 = pt >> 1, c0 = (pt & 1) << 5;
  int rsw = r0 & 7;                              // write-side swizzle key
  const int t0 = p ? 18 : 0;
  const int t1 = p ? 35 : 18;

  u32x4 kr[4], vr[4];
  // load tile t0
  {
    const unsigned short* kp = Kb + ((size_t)bh*2048 + t0*64 + r0)*64 + c0;
    const unsigned short* vp = VtG + ((size_t)bh*64 + r0)*2048 + t0*64 + c0;
    #pragma unroll
    for (int jj = 0; jj < 4; ++jj){
      kr[jj] = *(const u32x4*)(kp + 8*jj);
      vr[jj] = *(const u32x4*)(vp + 8*jj);
    }
  }
  // write buf0 with tile t0 (no barrier needed before: nothing read yet)
  {
    short* k0 = (short*)(smem + p*8192);
    short* v0 = (short*)(smem + 32768 + p*8192);
    #pragma unroll
    for (int jj = 0; jj < 4; ++jj){
      int gsw = ((((pt & 1) << 2) | jj) ^ rsw) << 3;
      *(u32x4*)(&k0[r0*64 + gsw]) = kr[jj];
      *(u32x4*)(&v0[r0*64 + gsw]) = vr[jj];
    }
  }
  // load tile t0+1 into regs (written to buf1 during iter 0)
  if (t0 + 1 < t1){
    const unsigned short* kp = Kb + ((size_t)bh*2048 + (t0 + 1)*64 + r0)*64 + c0;
    const unsigned short* vp = VtG + ((size_t)bh*64 + r0)*2048 + (t0 + 1)*64 + c0;
    #pragma unroll
    for (int jj = 0; jj < 4; ++jj){
      kr[jj] = *(const u32x4*)(kp + 8*jj);
      vr[jj] = *(const u32x4*)(vp + 8*jj);
    }
  }
  __syncthreads();                               // buf0 visible

  for (int it = 0; it < 18; ++it){
    int tile = t0 + it;
    bool valid = tile < t1;
    int d = it & 1;
    short* curK = (short*)(smem + d*16384 + p*8192);
    short* curV = (short*)(smem + 32768 + d*16384 + p*8192);

    // 1) write NEXT tile (data in kr/vr) into the other buffer
    if (tile + 1 < t1){
      short* nxtK = (short*)(smem + (d^1)*16384 + p*8192);
      short* nxtV = (short*)(smem + 32768 + (d^1)*16384 + p*8192);
      #pragma unroll
      for (int jj = 0; jj < 4; ++jj){
        int gsw = ((((pt & 1) << 2) | jj) ^ rsw) << 3;
        *(u32x4*)(&nxtK[r0*64 + gsw]) = kr[jj];
        *(u32x4*)(&nxtV[r0*64 + gsw]) = vr[jj];
      }
    }
    // 2) issue loads for tile+2 (lands during compute; consumed next iter)
    if (tile + 2 < t1){
      int nt = tile + 2;
      bool ext = nt >= 32;
      int kb = ext ? (nt - 32)*64 : nt*64;
      const unsigned short* kp = ext ? (kext + ((size_t)b*192 + kb + r0)*64 + c0)
                                     : (Kb + ((size_t)bh*2048 + kb + r0)*64 + c0);
      const unsigned short* vp = ext ? (vext_t + ((size_t)b*64 + r0)*192 + kb + c0)
                                     : (VtG + ((size_t)bh*64 + r0)*2048 + kb + c0);
      #pragma unroll
      for (int jj = 0; jj < 4; ++jj){
        kr[jj] = *(const u32x4*)(kp + 8*jj);
        vr[jj] = *(const u32x4*)(vp + 8*jj);
      }
    }
    // 3) compute current tile from buf[d]
    if (valid){
      bf16x8 kf[4][2];
      #pragma unroll
      for (int st = 0; st < 4; ++st){
        kf[st][0] = *(const bf16x8*)(&curK[(st*16 + lm)*64 + ((q       ^ esw) << 3)]);
        kf[st][1] = *(const bf16x8*)(&curK[(st*16 + lm)*64 + (((4 + q) ^ esw) << 3)]);
      }

      #pragma unroll
      for (int qp = 0; qp < 2; ++qp){            // qq pairs {0,1},{2,3}
        f32x4 s[2][4];
        #pragma unroll
        for (int qh = 0; qh < 2; ++qh){
          int qq = qp*2 + qh;
          #pragma unroll
          for (int st = 0; st < 4; ++st){
            f32x4 z = {};
            z = __builtin_amdgcn_mfma_f32_16x16x32_bf16(kf[st][0], qf[qq][0], z, 0, 0, 0);
            s[qh][st] = __builtin_amdgcn_mfma_f32_16x16x32_bf16(kf[st][1], qf[qq][1], z, 0, 0, 0);
          }
        }
        if (tile == 34){                         // keys 128..191: only 128 valid
          #pragma unroll
          for (int qh = 0; qh < 2; ++qh)
            #pragma unroll
            for (int st = 0; st < 4; ++st)
              #pragma unroll
              for (int rr = 0; rr < 4; ++rr){
                int key = 128 + st*16 + q*4 + rr;
                if (key >= 129) s[qh][st][rr] = -1e30f;
              }
        }
        bf16x8 pb[2][2];
        #pragma unroll
        for (int qh = 0; qh < 2; ++qh){          // per-qh: exp, pack->pw, read
          float sm = 0.f;
          #pragma unroll
          for (int st = 0; st < 4; ++st)
            #pragma unroll
            for (int rr = 0; rr < 4; ++rr){
              float pv = __builtin_amdgcn_exp2f(s[qh][st][rr]);
              s[qh][st][rr] = pv; sm += pv;
            }
          l_i[qp*2 + qh] += sm;
          #pragma unroll
          for (int st = 0; st < 4; ++st){
            u32x2 pkd;
            pkd[0] = pk2(s[qh][st][0], s[qh][st][1]);
            pkd[1] = pk2(s[qh][st][2], s[qh][st][3]);
            int gsw = ((((st << 1) | (q >> 1)) ^ esw) << 3) + ((q & 1) << 2);
            *(u32x2*)(&pw[lm*64 + gsw]) = pkd;
          }
          // read back (own-wave region, in-order DS pipe -> no barrier)
          bf16x4 a0 = *(const bf16x4*)(&pw[lm*64 + ((q       ^ esw) << 3)]);
          bf16x4 a1 = *(const bf16x4*)(&pw[lm*64 + ((q       ^ esw) << 3) + 4]);
          bf16x4 a2 = *(const bf16x4*)(&pw[lm*64 + (((4 + q) ^ esw) << 3)]);
          bf16x4 a3 = *(const bf16x4*)(&pw[lm*64 + (((4 + q) ^ esw) << 3) + 4]);
          pb[qh][0] = __builtin_shufflevector(a0, a1, 0,1,2,3,4,5,6,7);
          pb[qh][1] = __builtin_shufflevector(a2, a3, 0,1,2,3,4,5,6,7);
        }
        #pragma unroll
        for (int ds = 0; ds < 4; ++ds){
          bf16x8 af0 = *(const bf16x8*)(&curV[(ds*16 + lm)*64 + ((q       ^ esw) << 3)]);
          bf16x8 af1 = *(const bf16x8*)(&curV[(ds*16 + lm)*64 + (((4 + q) ^ esw) << 3)]);
          #pragma unroll
          for (int qh = 0; qh < 2; ++qh){
            int qq = qp*2 + qh;
            o[ds][qq] = __builtin_amdgcn_mfma_f32_16x16x32_bf16(af0, pb[qh][0], o[ds][qq], 0, 0, 0);
            o[ds][qq] = __builtin_amdgcn_mfma_f32_16x16x32_bf16(af1, pb[qh][1], o[ds][qq], 0, 0, 0);
          }
        }
      }
    }
    // 4) single barrier: publishes this iter's staging writes; also ensures
    //    everyone finished reading buf[d] before it is overwritten in it+2.
    __syncthreads();
  }

  // ---- merge the two key-halves (additive: no rescale needed) ----
  // overlay at smem offset 0: 2 waves x 64 lanes x 68 floats = 34816 B
  // (K bufs [0,32768) + start of V bufs — all dead past the loop's barrier)
  float* mb = (float*)smem;
  float* reg = mb + lw*4352 + lane*68;
  if (p == 1){
    #pragma unroll
    for (int ds = 0; ds < 4; ++ds)
      #pragma unroll
      for (int qq = 0; qq < 4; ++qq)
        *(f32x4*)(reg + (ds*4 + qq)*4) = o[ds][qq];
    #pragma unroll
    for (int qq = 0; qq < 4; ++qq) reg[64 + qq] = l_i[qq];
  }
  __syncthreads();
  if (p == 0){
    #pragma unroll
    for (int qq = 0; qq < 4; ++qq){
      #pragma unroll
      for (int ds = 0; ds < 4; ++ds){
        f32x4 ov = *(const f32x4*)(reg + (ds*4 + qq)*4);
        o[ds][qq] += ov;
      }
      float l = l_i[qq] + reg[64 + qq];
      l += __shfl_xor(l, 16);
      l += __shfl_xor(l, 32);
      float inv = 1.0f / l;
      int n = qt*128 + lw*64 + qq*16 + lm;
      size_t base = ((size_t)b*2048 + n)*1024 + h*64 + q*4;
      #pragma unroll
      for (int ds = 0; ds < 4; ++ds){
        ushort4 u;
        u.x = f2b(o[ds][qq][0] * inv); u.y = f2b(o[ds][qq][1] * inv);
        u.z = f2b(o[ds][qq][2] * inv); u.w = f2b(o[ds][qq][3] * inv);
        *(ushort4*)(Ob + base + ds*16) = u;
      }
    }
  }
}

// ---------------------------------------------------------------------------
extern "C" void kernel_launch(void* const* d_in, const int* in_sizes, int n_in,
                              void* d_out, int out_size, void* d_ws, size_t ws_size,
                              hipStream_t stream)
{
  const float* x       = (const float*)d_in[0];
  const float* c_emb   = (const float*)d_in[1];
  const float* ln_g    = (const float*)d_in[2];
  const float* ln_b    = (const float*)d_in[3];
  const float* ctx_g   = (const float*)d_in[4];
  const float* ctx_b   = (const float*)d_in[5];
  const float* W_ctx   = (const float*)d_in[6];
  const float* b_ctx   = (const float*)d_in[7];
  const float* W_q     = (const float*)d_in[8];
  const float* W_kv    = (const float*)d_in[9];
  const float* null_kv = (const float*)d_in[10];
  const float* W_out   = (const float*)d_in[11];
  const float* oln_g   = (const float*)d_in[12];
  const float* oln_b   = (const float*)d_in[13];
  float* out = (float*)d_out;

  char* p = (char*)d_ws;
  unsigned short* xn     = (unsigned short*)p; p += (size_t)4096*1024*2;
  unsigned short* Wqkv_t = (unsigned short*)p; p += (size_t)3072*1024*2;
  unsigned short* Wout_t = (unsigned short*)p; p += (size_t)1024*1024*2;
  unsigned short* Qb     = (unsigned short*)p; p += (size_t)32*2048*64*2;
  unsigned short* Kb     = (unsigned short*)p; p += (size_t)32*2048*64*2;
  unsigned short* VtG    = (unsigned short*)p; p += (size_t)32*64*2048*2;
  unsigned short* kext   = (unsigned short*)p; p += (size_t)2*192*64*2;
  unsigned short* vext_t = (unsigned short*)p; p += (size_t)2*64*192*2;
  unsigned short* aout   = (unsigned short*)p; p += (size_t)4096*1024*2;
  float*          ptmp   = (float*)p;          p += (size_t)4096*1024*4;
  // split-K partial #2 overlays Qb+Kb (16 MB, dead after attn completes)
  float*          ptmp1  = (float*)Qb;

  prologue_kernel<<<5376, 256, 0, stream>>>(
      W_q, W_kv, W_out, Wqkv_t, Wout_t,
      x, ln_g, ln_b, xn,
      c_emb, ctx_g, ctx_b, W_ctx, b_ctx, null_kv, kext, vext_t);
  gemm_qkv_kernel<<<768, 256, 0, stream>>>(xn, Wqkv_t, Qb, Kb, VtG);
  attn_kernel<<<512, 256, 0, stream>>>(Qb, Kb, VtG, kext, vext_t, aout);
  gemm_out_kernel<<<512, 256, 0, stream>>>(aout, Wout_t, ptmp, ptmp1);
  ln1024f_kernel<<<4096, 256, 0, stream>>>(ptmp, ptmp1, oln_g, oln_b, out);
}

// Round 15
// 259.022 us; speedup vs baseline: 1.0317x; 1.0060x over previous
//
#include <hip/hip_runtime.h>
#include <cstdint>
#include <cstddef>

typedef __attribute__((ext_vector_type(8))) short bf16x8;
typedef __attribute__((ext_vector_type(4))) short bf16x4;
typedef __attribute__((ext_vector_type(4))) float f32x4;
typedef __attribute__((ext_vector_type(4))) unsigned int u32x4;
typedef __attribute__((ext_vector_type(2))) unsigned int u32x2;

__device__ inline unsigned short f2b(float f){
  unsigned int u = __float_as_uint(f);
  u += 0x7fffu + ((u >> 16) & 1u);
  return (unsigned short)(u >> 16);
}
// pack two fp32 -> bf16 pair via v_perm (probs >= 0, round-half-up)
__device__ inline unsigned int pk2(float a, float b){
  unsigned int ua = __float_as_uint(a) + 0x8000u;
  unsigned int ub = __float_as_uint(b) + 0x8000u;
  return __builtin_amdgcn_perm(ub, ua, 0x07060302u);
}
// async global->LDS, 16B/lane; LDS dest = wave-uniform base + lane*16
__device__ inline void gl2lds16(const void* g, void* l){
  __builtin_amdgcn_global_load_lds(
      (const __attribute__((address_space(1))) unsigned int*)g,
      (__attribute__((address_space(3))) unsigned int*)l, 16, 0, 0);
}

#define QSCALE 0.18033688011112042f   // 0.125 * log2(e): softmax in log2 domain

// ---------------------------------------------------------------------------
// Fused prologue (unchanged from R7): wcvt | ln->bf16 | ctx in one dispatch.
// ---------------------------------------------------------------------------
__global__ __launch_bounds__(256) void prologue_kernel(
    const float* __restrict__ Wq, const float* __restrict__ Wkv,
    const float* __restrict__ Wout,
    unsigned short* __restrict__ Wqkv_t, unsigned short* __restrict__ Wout_t,
    const float* __restrict__ X, const float* __restrict__ G,
    const float* __restrict__ Bb, unsigned short* __restrict__ xn,
    const float* __restrict__ Cemb, const float* __restrict__ cG,
    const float* __restrict__ cBb, const float* __restrict__ Wctx,
    const float* __restrict__ bctx, const float* __restrict__ nullkv,
    unsigned short* __restrict__ kext, unsigned short* __restrict__ vext_t)
{
  __shared__ __align__(16) char fsm[9216];
  int bid = blockIdx.x;
  int t = threadIdx.x;

  if (bid < 1024){
    short* tile = (short*)fsm;
    int cg0 = (bid & 63) * 64;
    int kt  = (bid >> 6) * 64;
    const float* src; int ld; int col0; unsigned short* dst; int drow0;
    if (cg0 < 1024)      { src = Wq;   ld = 1024; col0 = cg0;        dst = Wqkv_t; drow0 = cg0; }
    else if (cg0 < 3072) { src = Wkv;  ld = 2048; col0 = cg0 - 1024; dst = Wqkv_t; drow0 = cg0; }
    else                 { src = Wout; ld = 1024; col0 = cg0 - 3072; dst = Wout_t; drow0 = cg0 - 3072; }
    #pragma unroll
    for (int i = 0; i < 16; ++i){
      int lin = t + 256*i;
      int k = lin >> 6, c = lin & 63;
      tile[k*72 + c] = (short)f2b(src[(size_t)(kt + k)*ld + col0 + c]);
    }
    __syncthreads();
    #pragma unroll
    for (int i = 0; i < 16; ++i){
      int lin = t + 256*i;
      int c = lin >> 6, k = lin & 63;
      dst[(size_t)(drow0 + c)*1024 + kt + k] = (unsigned short)tile[k*72 + c];
    }
  } else if (bid < 5120){
    int row = bid - 1024;
    float* red = (float*)fsm;
    float4 x = ((const float4*)(X + (size_t)row*1024))[t];
    float s  = x.x + x.y + x.z + x.w;
    float s2 = x.x*x.x + x.y*x.y + x.z*x.z + x.w*x.w;
    #pragma unroll
    for (int o = 32; o > 0; o >>= 1){ s += __shfl_down(s, o); s2 += __shfl_down(s2, o); }
    int w = t >> 6;
    if ((t & 63) == 0){ red[w] = s; red[4 + w] = s2; }
    __syncthreads();
    float mu  = (red[0]+red[1]+red[2]+red[3]) * (1.0f/1024.0f);
    float var = (red[4]+red[5]+red[6]+red[7]) * (1.0f/1024.0f) - mu*mu;
    float rstd = rsqrtf(var + 1e-5f);
    float4 g = ((const float4*)G)[t];
    float4 b = ((const float4*)Bb)[t];
    ushort4 u;
    u.x = f2b((x.x-mu)*rstd*g.x + b.x);
    u.y = f2b((x.y-mu)*rstd*g.y + b.y);
    u.z = f2b((x.z-mu)*rstd*g.z + b.z);
    u.w = f2b((x.w-mu)*rstd*g.w + b.w);
    ((ushort4*)xn)[(size_t)row*256 + t] = u;
  } else {
    int row = bid - 5120;            // 0..255 (b*128 + m)
    int b = row >> 7, m = row & 127;
    bool act = t < 128;
    float* red  = (float*)fsm;
    float* xns  = (float*)(fsm + 16);
    if (act && row < 128){
      int b2 = row >> 6, fr = row & 63;
      int frow = (fr == 0) ? 0 : (128 + fr);
      if (t < 64){
        kext[((size_t)b2*192 + frow)*64 + t] = (frow == 0) ? f2b(nullkv[t]) : (unsigned short)0;
      } else {
        int d = t - 64;
        vext_t[((size_t)b2*64 + d)*192 + frow] = (frow == 0) ? f2b(nullkv[64 + d]) : (unsigned short)0;
      }
    }
    const float* xr = Cemb + (size_t)row*768;
    float v[6]; float s = 0.f, s2 = 0.f;
    if (act){
      #pragma unroll
      for (int j = 0; j < 6; ++j){ float xv = xr[t + 128*j]; v[j] = xv; s += xv; s2 += xv*xv; }
      #pragma unroll
      for (int o = 32; o > 0; o >>= 1){ s += __shfl_down(s, o); s2 += __shfl_down(s2, o); }
      int w = t >> 6;
      if ((t & 63) == 0){ red[w] = s; red[2 + w] = s2; }
    }
    __syncthreads();
    if (act){
      float mu  = (red[0]+red[1]) * (1.0f/768.0f);
      float var = (red[2]+red[3]) * (1.0f/768.0f) - mu*mu;
      float rstd = rsqrtf(var + 1e-5f);
      #pragma unroll
      for (int j = 0; j < 6; ++j){ int c = t + 128*j; xns[c] = (v[j]-mu)*rstd*cG[c] + cBb[c]; }
    }
    __syncthreads();
    if (act){
      float acc = bctx[t];
      #pragma unroll 8
      for (int j = 0; j < 768; ++j) acc += xns[j] * Wctx[j*128 + t];
      unsigned short hv = f2b(acc);
      if (t < 64) kext[((size_t)b*192 + 1 + m)*64 + t] = hv;
      else        vext_t[((size_t)b*64 + (t - 64))*192 + 1 + m] = hv;
    }
  }
}

// ---------------------------------------------------------------------------
// Final LayerNorm over 1024 cols; input = P0 + P1 (split-K partial sums).
// ---------------------------------------------------------------------------
__global__ __launch_bounds__(256) void ln1024f_kernel(
    const float* __restrict__ P0, const float* __restrict__ P1,
    const float* __restrict__ G, const float* __restrict__ Bb,
    float* __restrict__ out)
{
  int row = blockIdx.x, t = threadIdx.x;
  float4 xa = ((const float4*)(P0 + (size_t)row*1024))[t];
  float4 xb = ((const float4*)(P1 + (size_t)row*1024))[t];
  float4 x;
  x.x = xa.x + xb.x; x.y = xa.y + xb.y; x.z = xa.z + xb.z; x.w = xa.w + xb.w;
  float s  = x.x + x.y + x.z + x.w;
  float s2 = x.x*x.x + x.y*x.y + x.z*x.z + x.w*x.w;
  #pragma unroll
  for (int o = 32; o > 0; o >>= 1){ s += __shfl_down(s, o); s2 += __shfl_down(s2, o); }
  __shared__ float red[8];
  int w = t >> 6;
  if ((t & 63) == 0){ red[w] = s; red[4 + w] = s2; }
  __syncthreads();
  float mu  = (red[0]+red[1]+red[2]+red[3]) * (1.0f/1024.0f);
  float var = (red[4]+red[5]+red[6]+red[7]) * (1.0f/1024.0f) - mu*mu;
  float rstd = rsqrtf(var + 1e-5f);
  float4 g = ((const float4*)G)[t];
  float4 b = ((const float4*)Bb)[t];
  float4 y;
  y.x = (x.x-mu)*rstd*g.x + b.x;
  y.y = (x.y-mu)*rstd*g.y + b.y;
  y.z = (x.z-mu)*rstd*g.z + b.z;
  y.w = (x.w-mu)*rstd*g.w + b.w;
  ((float4*)out)[(size_t)row*256 + t] = y;
}

// ---------------------------------------------------------------------------
// bt-GEMM mainloop, K-range parameterized (split-K support).
// ---------------------------------------------------------------------------
#define GEMM_MAINLOOP_K(A_, Bt_, tM_, tN_, KLO_, KHI_)                          \
  __shared__ __align__(16) short sA[128*64];                                    \
  __shared__ __align__(16) short sB[128*64];                                    \
  int t = threadIdx.x, w = t >> 6, lane = t & 63;                               \
  int wm = w & 1, wn = w >> 1, lm = lane & 15, q = lane >> 4;                   \
  int grow = lane >> 3;                                                         \
  int gchk = ((lane & 7) ^ grow) << 3;                                          \
  f32x4 acc[4][4] = {};                                                         \
  const unsigned short* Aw = A_ + (size_t)(tM_ + w*32 + grow)*1024 + gchk;      \
  const unsigned short* Bw = Bt_ + (size_t)(tN_ + w*32 + grow)*1024 + gchk;     \
  for (int kk = (KLO_); kk < (KHI_); kk += 64){                                 \
    __syncthreads();                                                            \
    gl2lds16(Aw + kk,            &sA[(w*32     )*64]);                          \
    gl2lds16(Aw + kk +  8*1024,  &sA[(w*32 +  8)*64]);                          \
    gl2lds16(Aw + kk + 16*1024,  &sA[(w*32 + 16)*64]);                          \
    gl2lds16(Aw + kk + 24*1024,  &sA[(w*32 + 24)*64]);                          \
    gl2lds16(Bw + kk,            &sB[(w*32     )*64]);                          \
    gl2lds16(Bw + kk +  8*1024,  &sB[(w*32 +  8)*64]);                          \
    gl2lds16(Bw + kk + 16*1024,  &sB[(w*32 + 16)*64]);                          \
    gl2lds16(Bw + kk + 24*1024,  &sB[(w*32 + 24)*64]);                          \
    __syncthreads();                                                            \
    bf16x8 af[4][2], bfr[4][2];                                                 \
    _Pragma("unroll")                                                           \
    for (int i = 0; i < 4; ++i){                                                \
      int ra = wm*64 + i*16 + lm, rb = wn*64 + i*16 + lm;                       \
      _Pragma("unroll")                                                         \
      for (int hh = 0; hh < 2; ++hh){                                           \
        int sw = ((hh*4 + q) ^ (lm & 7)) << 3;                                  \
        af[i][hh]  = *(const bf16x8*)(&sA[ra*64 + sw]);                         \
        bfr[i][hh] = *(const bf16x8*)(&sB[rb*64 + sw]);                         \
      }                                                                         \
    }                                                                           \
    _Pragma("unroll")                                                           \
    for (int hh = 0; hh < 2; ++hh)                                              \
      _Pragma("unroll")                                                         \
      for (int i = 0; i < 4; ++i)                                               \
        _Pragma("unroll")                                                       \
        for (int j = 0; j < 4; ++j)                                             \
          acc[i][j] = __builtin_amdgcn_mfma_f32_16x16x32_bf16(af[i][hh], bfr[j][hh], acc[i][j], 0, 0, 0); \
  }

#define GEMM_MAINLOOP(A_, Bt_, tM_, tN_) GEMM_MAINLOOP_K(A_, Bt_, tM_, tN_, 0, 1024)

// QKV GEMM (1D grid 768). XCD swizzle: 8 M-tiles x 12 N-tiles per XCD.
__global__ __launch_bounds__(256) void gemm_qkv_kernel(
    const unsigned short* __restrict__ A, const unsigned short* __restrict__ Bt,
    unsigned short* __restrict__ Qb, unsigned short* __restrict__ Kb,
    unsigned short* __restrict__ VtG)
{
  int id = blockIdx.x;
  int xcd = id & 7, r = id >> 3;          // r in [0,96)
  int tM = ((xcd >> 1)*8 + (r & 7)) * 128;
  int tN = ((xcd & 1)*12 + (r >> 3)) * 128;   // [0,24) -> Q/K/V regions
  GEMM_MAINLOOP(A, Bt, tM, tN)
  if (tN < 1024){                 // Q region
    #pragma unroll
    for (int i = 0; i < 4; ++i){
      int R0 = tM + wm*64 + i*16 + q*4;
      int b = R0 >> 11, n = R0 & 2047;
      #pragma unroll
      for (int j = 0; j < 4; ++j){
        int Cg = tN + wn*64 + j*16 + lm;
        int h = Cg >> 6, d = Cg & 63;
        size_t base = ((((size_t)(b*16 + h) << 11) | n) << 6) + d;
        #pragma unroll
        for (int rr = 0; rr < 4; ++rr)
          Qb[base + (size_t)rr*64] = f2b(acc[i][j][rr] * QSCALE);
      }
    }
  } else if (tN < 2048){          // K region
    #pragma unroll
    for (int i = 0; i < 4; ++i){
      int R0 = tM + wm*64 + i*16 + q*4;
      int b = R0 >> 11, n = R0 & 2047;
      #pragma unroll
      for (int j = 0; j < 4; ++j){
        int c2 = tN - 1024 + wn*64 + j*16 + lm;
        int h = c2 >> 6, d = c2 & 63;
        size_t base = ((((size_t)(b*16 + h) << 11) | n) << 6) + d;
        #pragma unroll
        for (int rr = 0; rr < 4; ++rr)
          Kb[base + (size_t)rr*64] = f2b(acc[i][j][rr]);
      }
    }
  } else {                        // V region -> transposed, packed 8B stores
    #pragma unroll
    for (int i = 0; i < 4; ++i){
      int R0 = tM + wm*64 + i*16 + q*4;
      int b = R0 >> 11, n = R0 & 2047;
      #pragma unroll
      for (int j = 0; j < 4; ++j){
        int c2 = tN - 2048 + wn*64 + j*16 + lm;
        int h = c2 >> 6, d = c2 & 63;
        ushort4 u;
        u.x = f2b(acc[i][j][0]); u.y = f2b(acc[i][j][1]);
        u.z = f2b(acc[i][j][2]); u.w = f2b(acc[i][j][3]);
        *(ushort4*)(VtG + ((size_t)(b*16 + h)*64 + d)*2048 + n) = u;
      }
    }
  }
}

// Out-proj GEMM, split-K 2-way (kept from R8: non-attn time 198.5 -> 193.9).
__global__ __launch_bounds__(256) void gemm_out_kernel(
    const unsigned short* __restrict__ A, const unsigned short* __restrict__ Bt,
    float* __restrict__ C0, float* __restrict__ C1)
{
  int id = blockIdx.x;
  int xcd = id & 7, r = id >> 3;          // r in [0,64)
  int ks = r & 1;                          // K slice
  int r2 = r >> 1;                         // [0,32)
  int tM = ((r2 & 3)*8 + xcd) * 128;
  int tN = (r2 >> 2) * 128;                // [0,8)
  float* C = ks ? C1 : C0;
  GEMM_MAINLOOP_K(A, Bt, tM, tN, ks*512, ks*512 + 512)
  #pragma unroll
  for (int i = 0; i < 4; ++i){
    int R0 = tM + wm*64 + i*16 + q*4;
    #pragma unroll
    for (int j = 0; j < 4; ++j){
      int Cg = tN + wn*64 + j*16 + lm;
      #pragma unroll
      for (int rr = 0; rr < 4; ++rr)
        C[(size_t)(R0 + rr)*1024 + Cg] = acc[i][j][rr];
    }
  }
}

// ---------------------------------------------------------------------------
// Flash attention — EXACT R9 structure (banked best: attn 65.1us, total
// 259.5us), restored after R14's double-buffer lost 3.4us (barrier savings <
// DS-pipe cost of staging writes ahead of compute; reconfirms m99/m100).
// Session ledger: R2 restructure, R6 L2-direct, R8/R13 64-query geometry,
// R14 dbuf ALL lost to this 2-barrier form; only the XOR swizzle won (-3.1us).
// ONE addition vs R9: s_setprio(1)/(0) around the QK^T and PV MFMA clusters
// (m191: +4-7% on attn with independent blocks per CU; pure hint, zero
// correctness risk; kill: attn > 66us -> strip).
// 128-query blocks, grid 512, 2 pairs x 18/17 key tiles, additive no-max
// log2-softmax, merge in dead K/V LDS after final barrier.
// LDS carve (40960 B): [0,16384) K | [16384,32768) Vt | [32768,40960) P.
// K/V: 64x64 shorts, granule g at g^(row&7) (write rsw=r0&7, read esw=lm&7).
// ---------------------------------------------------------------------------
__global__ __launch_bounds__(256, 2) void attn_kernel(
    const unsigned short* __restrict__ Qb, const unsigned short* __restrict__ Kb,
    const unsigned short* __restrict__ VtG, const unsigned short* __restrict__ kext,
    const unsigned short* __restrict__ vext_t, unsigned short* __restrict__ Ob)
{
  __shared__ __align__(16) char smem[40960];
  int id = blockIdx.x;
  int xcd = id & 7, slot = id >> 3;              // 4 bh per XCD for L2 locality
  int bh = xcd*4 + (slot >> 4);
  int qt = slot & 15;
  int b = bh >> 4, h = bh & 15;
  int t = threadIdx.x, w = t >> 6, lane = t & 63;
  int p = w >> 1, lw = w & 1;
  int lm = lane & 15, q = lane >> 4;
  int esw = lm & 7;                              // read-side swizzle key

  short* myK = (short*)(smem + p*8192);
  short* myV = (short*)(smem + 16384 + p*8192);
  short* pw  = (short*)(smem + 32768 + w*2048);

  const unsigned short* Qbase = Qb + ((size_t)bh*2048 + qt*128 + lw*64)*64;
  bf16x8 qf[4][2];
  #pragma unroll
  for (int qq = 0; qq < 4; ++qq){
    qf[qq][0] = *(const bf16x8*)(Qbase + (size_t)(qq*16 + lm)*64 + q*8);
    qf[qq][1] = *(const bf16x8*)(Qbase + (size_t)(qq*16 + lm)*64 + q*8 + 32);
  }

  f32x4 o[4][4] = {};                            // [ds][qq]
  float l_i[4] = {0.f, 0.f, 0.f, 0.f};

  // staging within the pair: 128 threads, row r0, 32-short half c0
  int pt = t & 127;
  int r0 = pt >> 1, c0 = (pt & 1) << 5;
  int rsw = r0 & 7;                              // write-side swizzle key
  const int t0 = p ? 18 : 0;
  const int t1 = p ? 35 : 18;

  u32x4 kr[4], vr[4];
  {
    const unsigned short* kp = Kb + ((size_t)bh*2048 + t0*64 + r0)*64 + c0;
    const unsigned short* vp = VtG + ((size_t)bh*64 + r0)*2048 + t0*64 + c0;
    #pragma unroll
    for (int jj = 0; jj < 4; ++jj){
      kr[jj] = *(const u32x4*)(kp + 8*jj);
      vr[jj] = *(const u32x4*)(vp + 8*jj);
    }
  }

  for (int it = 0; it < 18; ++it){
    int tile = t0 + it;
    bool valid = tile < t1;
    __syncthreads();
    if (valid){
      #pragma unroll
      for (int jj = 0; jj < 4; ++jj){
        int gsw = ((((pt & 1) << 2) | jj) ^ rsw) << 3;
        *(u32x4*)(&myK[r0*64 + gsw]) = kr[jj];
        *(u32x4*)(&myV[r0*64 + gsw]) = vr[jj];
      }
    }
    __syncthreads();

    int nt = tile + 1;
    if (nt < t1){                                // prefetch next tile
      bool ext = nt >= 32;
      int kb = ext ? (nt - 32)*64 : nt*64;
      const unsigned short* kp = ext ? (kext + ((size_t)b*192 + kb + r0)*64 + c0)
                                     : (Kb + ((size_t)bh*2048 + kb + r0)*64 + c0);
      const unsigned short* vp = ext ? (vext_t + ((size_t)b*64 + r0)*192 + kb + c0)
                                     : (VtG + ((size_t)bh*64 + r0)*2048 + kb + c0);
      #pragma unroll
      for (int jj = 0; jj < 4; ++jj){
        kr[jj] = *(const u32x4*)(kp + 8*jj);
        vr[jj] = *(const u32x4*)(vp + 8*jj);
      }
    }
    if (!valid) continue;                        // barriers already passed

    bf16x8 kf[4][2];
    #pragma unroll
    for (int st = 0; st < 4; ++st){
      kf[st][0] = *(const bf16x8*)(&myK[(st*16 + lm)*64 + ((q       ^ esw) << 3)]);
      kf[st][1] = *(const bf16x8*)(&myK[(st*16 + lm)*64 + (((4 + q) ^ esw) << 3)]);
    }

    #pragma unroll
    for (int qp = 0; qp < 2; ++qp){              // qq pairs {0,1},{2,3}
      f32x4 s[2][4];
      __builtin_amdgcn_s_setprio(1);             // QK^T MFMA cluster (m191)
      #pragma unroll
      for (int qh = 0; qh < 2; ++qh){
        int qq = qp*2 + qh;
        #pragma unroll
        for (int st = 0; st < 4; ++st){
          f32x4 z = {};
          z = __builtin_amdgcn_mfma_f32_16x16x32_bf16(kf[st][0], qf[qq][0], z, 0, 0, 0);
          s[qh][st] = __builtin_amdgcn_mfma_f32_16x16x32_bf16(kf[st][1], qf[qq][1], z, 0, 0, 0);
        }
      }
      __builtin_amdgcn_s_setprio(0);
      if (tile == 34){                           // keys 128..191: only 128 valid
        #pragma unroll
        for (int qh = 0; qh < 2; ++qh)
          #pragma unroll
          for (int st = 0; st < 4; ++st)
            #pragma unroll
            for (int rr = 0; rr < 4; ++rr){
              int key = 128 + st*16 + q*4 + rr;
              if (key >= 129) s[qh][st][rr] = -1e30f;
            }
      }
      bf16x8 pb[2][2];
      #pragma unroll
      for (int qh = 0; qh < 2; ++qh){            // per-qh: exp, pack->pw, read
        float sm = 0.f;
        #pragma unroll
        for (int st = 0; st < 4; ++st)
          #pragma unroll
          for (int rr = 0; rr < 4; ++rr){
            float pv = __builtin_amdgcn_exp2f(s[qh][st][rr]);
            s[qh][st][rr] = pv; sm += pv;
          }
        l_i[qp*2 + qh] += sm;
        #pragma unroll
        for (int st = 0; st < 4; ++st){
          u32x2 pkd;
          pkd[0] = pk2(s[qh][st][0], s[qh][st][1]);
          pkd[1] = pk2(s[qh][st][2], s[qh][st][3]);
          int gsw = ((((st << 1) | (q >> 1)) ^ esw) << 3) + ((q & 1) << 2);
          *(u32x2*)(&pw[lm*64 + gsw]) = pkd;
        }
        // read back (own-wave region, in-order DS pipe -> no barrier)
        bf16x4 a0 = *(const bf16x4*)(&pw[lm*64 + ((q       ^ esw) << 3)]);
        bf16x4 a1 = *(const bf16x4*)(&pw[lm*64 + ((q       ^ esw) << 3) + 4]);
        bf16x4 a2 = *(const bf16x4*)(&pw[lm*64 + (((4 + q) ^ esw) << 3)]);
        bf16x4 a3 = *(const bf16x4*)(&pw[lm*64 + (((4 + q) ^ esw) << 3) + 4]);
        pb[qh][0] = __builtin_shufflevector(a0, a1, 0,1,2,3,4,5,6,7);
        pb[qh][1] = __builtin_shufflevector(a2, a3, 0,1,2,3,4,5,6,7);
      }
      __builtin_amdgcn_s_setprio(1);             // PV MFMA cluster (m191)
      #pragma unroll
      for (int ds = 0; ds < 4; ++ds){
        bf16x8 af0 = *(const bf16x8*)(&myV[(ds*16 + lm)*64 + ((q       ^ esw) << 3)]);
        bf16x8 af1 = *(const bf16x8*)(&myV[(ds*16 + lm)*64 + (((4 + q) ^ esw) << 3)]);
        #pragma unroll
        for (int qh = 0; qh < 2; ++qh){
          int qq = qp*2 + qh;
          o[ds][qq] = __builtin_amdgcn_mfma_f32_16x16x32_bf16(af0, pb[qh][0], o[ds][qq], 0, 0, 0);
          o[ds][qq] = __builtin_amdgcn_mfma_f32_16x16x32_bf16(af1, pb[qh][1], o[ds][qq], 0, 0, 0);
        }
      }
      __builtin_amdgcn_s_setprio(0);
    }
  }

  // ---- merge the two key-halves (additive: no rescale needed) ----
  // overlay at smem offset 0: 2 waves x 64 lanes x 68 floats = 34816 B
  // (fits in the 40960 B allocation; K/Vt/P all dead past this barrier)
  float* mb = (float*)smem;
  float* reg = mb + lw*4352 + lane*68;
  __syncthreads();                               // all KV/P reads done
  if (p == 1){
    #pragma unroll
    for (int ds = 0; ds < 4; ++ds)
      #pragma unroll
      for (int qq = 0; qq < 4; ++qq)
        *(f32x4*)(reg + (ds*4 + qq)*4) = o[ds][qq];
    #pragma unroll
    for (int qq = 0; qq < 4; ++qq) reg[64 + qq] = l_i[qq];
  }
  __syncthreads();
  if (p == 0){
    #pragma unroll
    for (int qq = 0; qq < 4; ++qq){
      #pragma unroll
      for (int ds = 0; ds < 4; ++ds){
        f32x4 ov = *(const f32x4*)(reg + (ds*4 + qq)*4);
        o[ds][qq] += ov;
      }
      float l = l_i[qq] + reg[64 + qq];
      l += __shfl_xor(l, 16);
      l += __shfl_xor(l, 32);
      float inv = 1.0f / l;
      int n = qt*128 + lw*64 + qq*16 + lm;
      size_t base = ((size_t)b*2048 + n)*1024 + h*64 + q*4;
      #pragma unroll
      for (int ds = 0; ds < 4; ++ds){
        ushort4 u;
        u.x = f2b(o[ds][qq][0] * inv); u.y = f2b(o[ds][qq][1] * inv);
        u.z = f2b(o[ds][qq][2] * inv); u.w = f2b(o[ds][qq][3] * inv);
        *(ushort4*)(Ob + base + ds*16) = u;
      }
    }
  }
}

// ---------------------------------------------------------------------------
extern "C" void kernel_launch(void* const* d_in, const int* in_sizes, int n_in,
                              void* d_out, int out_size, void* d_ws, size_t ws_size,
                              hipStream_t stream)
{
  const float* x       = (const float*)d_in[0];
  const float* c_emb   = (const float*)d_in[1];
  const float* ln_g    = (const float*)d_in[2];
  const float* ln_b    = (const float*)d_in[3];
  const float* ctx_g   = (const float*)d_in[4];
  const float* ctx_b   = (const float*)d_in[5];
  const float* W_ctx   = (const float*)d_in[6];
  const float* b_ctx   = (const float*)d_in[7];
  const float* W_q     = (const float*)d_in[8];
  const float* W_kv    = (const float*)d_in[9];
  const float* null_kv = (const float*)d_in[10];
  const float* W_out   = (const float*)d_in[11];
  const float* oln_g   = (const float*)d_in[12];
  const float* oln_b   = (const float*)d_in[13];
  float* out = (float*)d_out;

  char* p = (char*)d_ws;
  unsigned short* xn     = (unsigned short*)p; p += (size_t)4096*1024*2;
  unsigned short* Wqkv_t = (unsigned short*)p; p += (size_t)3072*1024*2;
  unsigned short* Wout_t = (unsigned short*)p; p += (size_t)1024*1024*2;
  unsigned short* Qb     = (unsigned short*)p; p += (size_t)32*2048*64*2;
  unsigned short* Kb     = (unsigned short*)p; p += (size_t)32*2048*64*2;
  unsigned short* VtG    = (unsigned short*)p; p += (size_t)32*64*2048*2;
  unsigned short* kext   = (unsigned short*)p; p += (size_t)2*192*64*2;
  unsigned short* vext_t = (unsigned short*)p; p += (size_t)2*64*192*2;
  unsigned short* aout   = (unsigned short*)p; p += (size_t)4096*1024*2;
  float*          ptmp   = (float*)p;          p += (size_t)4096*1024*4;
  // split-K partial #2 overlays Qb+Kb (16 MB, dead after attn completes)
  float*          ptmp1  = (float*)Qb;

  prologue_kernel<<<5376, 256, 0, stream>>>(
      W_q, W_kv, W_out, Wqkv_t, Wout_t,
      x, ln_g, ln_b, xn,
      c_emb, ctx_g, ctx_b, W_ctx, b_ctx, null_kv, kext, vext_t);
  gemm_qkv_kernel<<<768, 256, 0, stream>>>(xn, Wqkv_t, Qb, Kb, VtG);
  attn_kernel<<<512, 256, 0, stream>>>(Qb, Kb, VtG, kext, vext_t, aout);
  gemm_out_kernel<<<512, 256, 0, stream>>>(aout, Wout_t, ptmp, ptmp1);
  ln1024f_kernel<<<4096, 256, 0, stream>>>(ptmp, ptmp1, oln_g, oln_b, out);
}

// Round 16
// 242.816 us; speedup vs baseline: 1.1006x; 1.0667x over previous
//
#include <hip/hip_runtime.h>
#include <cstdint>
#include <cstddef>

typedef __attribute__((ext_vector_type(8))) short bf16x8;
typedef __attribute__((ext_vector_type(4))) short bf16x4;
typedef __attribute__((ext_vector_type(4))) float f32x4;
typedef __attribute__((ext_vector_type(4))) unsigned int u32x4;
typedef __attribute__((ext_vector_type(2))) unsigned int u32x2;

__device__ inline unsigned short f2b(float f){
  unsigned int u = __float_as_uint(f);
  u += 0x7fffu + ((u >> 16) & 1u);
  return (unsigned short)(u >> 16);
}
// pack two fp32 -> bf16 pair via v_perm (low short = first arg, round-half-up)
__device__ inline unsigned int pk2(float a, float b){
  unsigned int ua = __float_as_uint(a) + 0x8000u;
  unsigned int ub = __float_as_uint(b) + 0x8000u;
  return __builtin_amdgcn_perm(ub, ua, 0x07060302u);
}
// async global->LDS, 16B/lane; LDS dest = wave-uniform base + lane*16
__device__ inline void gl2lds16(const void* g, void* l){
  __builtin_amdgcn_global_load_lds(
      (const __attribute__((address_space(1))) unsigned int*)g,
      (__attribute__((address_space(3))) unsigned int*)l, 16, 0, 0);
}

#define QSCALE 0.18033688011112042f   // 0.125 * log2(e): softmax in log2 domain

// ---------------------------------------------------------------------------
// Fused prologue (unchanged from R7): wcvt | ln->bf16 | ctx in one dispatch.
// ---------------------------------------------------------------------------
__global__ __launch_bounds__(256) void prologue_kernel(
    const float* __restrict__ Wq, const float* __restrict__ Wkv,
    const float* __restrict__ Wout,
    unsigned short* __restrict__ Wqkv_t, unsigned short* __restrict__ Wout_t,
    const float* __restrict__ X, const float* __restrict__ G,
    const float* __restrict__ Bb, unsigned short* __restrict__ xn,
    const float* __restrict__ Cemb, const float* __restrict__ cG,
    const float* __restrict__ cBb, const float* __restrict__ Wctx,
    const float* __restrict__ bctx, const float* __restrict__ nullkv,
    unsigned short* __restrict__ kext, unsigned short* __restrict__ vext_t)
{
  __shared__ __align__(16) char fsm[9216];
  int bid = blockIdx.x;
  int t = threadIdx.x;

  if (bid < 1024){
    short* tile = (short*)fsm;
    int cg0 = (bid & 63) * 64;
    int kt  = (bid >> 6) * 64;
    const float* src; int ld; int col0; unsigned short* dst; int drow0;
    if (cg0 < 1024)      { src = Wq;   ld = 1024; col0 = cg0;        dst = Wqkv_t; drow0 = cg0; }
    else if (cg0 < 3072) { src = Wkv;  ld = 2048; col0 = cg0 - 1024; dst = Wqkv_t; drow0 = cg0; }
    else                 { src = Wout; ld = 1024; col0 = cg0 - 3072; dst = Wout_t; drow0 = cg0 - 3072; }
    #pragma unroll
    for (int i = 0; i < 16; ++i){
      int lin = t + 256*i;
      int k = lin >> 6, c = lin & 63;
      tile[k*72 + c] = (short)f2b(src[(size_t)(kt + k)*ld + col0 + c]);
    }
    __syncthreads();
    #pragma unroll
    for (int i = 0; i < 16; ++i){
      int lin = t + 256*i;
      int c = lin >> 6, k = lin & 63;
      dst[(size_t)(drow0 + c)*1024 + kt + k] = (unsigned short)tile[k*72 + c];
    }
  } else if (bid < 5120){
    int row = bid - 1024;
    float* red = (float*)fsm;
    float4 x = ((const float4*)(X + (size_t)row*1024))[t];
    float s  = x.x + x.y + x.z + x.w;
    float s2 = x.x*x.x + x.y*x.y + x.z*x.z + x.w*x.w;
    #pragma unroll
    for (int o = 32; o > 0; o >>= 1){ s += __shfl_down(s, o); s2 += __shfl_down(s2, o); }
    int w = t >> 6;
    if ((t & 63) == 0){ red[w] = s; red[4 + w] = s2; }
    __syncthreads();
    float mu  = (red[0]+red[1]+red[2]+red[3]) * (1.0f/1024.0f);
    float var = (red[4]+red[5]+red[6]+red[7]) * (1.0f/1024.0f) - mu*mu;
    float rstd = rsqrtf(var + 1e-5f);
    float4 g = ((const float4*)G)[t];
    float4 b = ((const float4*)Bb)[t];
    ushort4 u;
    u.x = f2b((x.x-mu)*rstd*g.x + b.x);
    u.y = f2b((x.y-mu)*rstd*g.y + b.y);
    u.z = f2b((x.z-mu)*rstd*g.z + b.z);
    u.w = f2b((x.w-mu)*rstd*g.w + b.w);
    ((ushort4*)xn)[(size_t)row*256 + t] = u;
  } else {
    int row = bid - 5120;            // 0..255 (b*128 + m)
    int b = row >> 7, m = row & 127;
    bool act = t < 128;
    float* red  = (float*)fsm;
    float* xns  = (float*)(fsm + 16);
    if (act && row < 128){
      int b2 = row >> 6, fr = row & 63;
      int frow = (fr == 0) ? 0 : (128 + fr);
      if (t < 64){
        kext[((size_t)b2*192 + frow)*64 + t] = (frow == 0) ? f2b(nullkv[t]) : (unsigned short)0;
      } else {
        int d = t - 64;
        vext_t[((size_t)b2*64 + d)*192 + frow] = (frow == 0) ? f2b(nullkv[64 + d]) : (unsigned short)0;
      }
    }
    const float* xr = Cemb + (size_t)row*768;
    float v[6]; float s = 0.f, s2 = 0.f;
    if (act){
      #pragma unroll
      for (int j = 0; j < 6; ++j){ float xv = xr[t + 128*j]; v[j] = xv; s += xv; s2 += xv*xv; }
      #pragma unroll
      for (int o = 32; o > 0; o >>= 1){ s += __shfl_down(s, o); s2 += __shfl_down(s2, o); }
      int w = t >> 6;
      if ((t & 63) == 0){ red[w] = s; red[2 + w] = s2; }
    }
    __syncthreads();
    if (act){
      float mu  = (red[0]+red[1]) * (1.0f/768.0f);
      float var = (red[2]+red[3]) * (1.0f/768.0f) - mu*mu;
      float rstd = rsqrtf(var + 1e-5f);
      #pragma unroll
      for (int j = 0; j < 6; ++j){ int c = t + 128*j; xns[c] = (v[j]-mu)*rstd*cG[c] + cBb[c]; }
    }
    __syncthreads();
    if (act){
      float acc = bctx[t];
      #pragma unroll 8
      for (int j = 0; j < 768; ++j) acc += xns[j] * Wctx[j*128 + t];
      unsigned short hv = f2b(acc);
      if (t < 64) kext[((size_t)b*192 + 1 + m)*64 + t] = hv;
      else        vext_t[((size_t)b*64 + (t - 64))*192 + 1 + m] = hv;
    }
  }
}

// ---------------------------------------------------------------------------
// Final LayerNorm over 1024 cols; input = P0 + P1 (split-K partial sums).
// ---------------------------------------------------------------------------
__global__ __launch_bounds__(256) void ln1024f_kernel(
    const float* __restrict__ P0, const float* __restrict__ P1,
    const float* __restrict__ G, const float* __restrict__ Bb,
    float* __restrict__ out)
{
  int row = blockIdx.x, t = threadIdx.x;
  float4 xa = ((const float4*)(P0 + (size_t)row*1024))[t];
  float4 xb = ((const float4*)(P1 + (size_t)row*1024))[t];
  float4 x;
  x.x = xa.x + xb.x; x.y = xa.y + xb.y; x.z = xa.z + xb.z; x.w = xa.w + xb.w;
  float s  = x.x + x.y + x.z + x.w;
  float s2 = x.x*x.x + x.y*x.y + x.z*x.z + x.w*x.w;
  #pragma unroll
  for (int o = 32; o > 0; o >>= 1){ s += __shfl_down(s, o); s2 += __shfl_down(s2, o); }
  __shared__ float red[8];
  int w = t >> 6;
  if ((t & 63) == 0){ red[w] = s; red[4 + w] = s2; }
  __syncthreads();
  float mu  = (red[0]+red[1]+red[2]+red[3]) * (1.0f/1024.0f);
  float var = (red[4]+red[5]+red[6]+red[7]) * (1.0f/1024.0f) - mu*mu;
  float rstd = rsqrtf(var + 1e-5f);
  float4 g = ((const float4*)G)[t];
  float4 b = ((const float4*)Bb)[t];
  float4 y;
  y.x = (x.x-mu)*rstd*g.x + b.x;
  y.y = (x.y-mu)*rstd*g.y + b.y;
  y.z = (x.z-mu)*rstd*g.z + b.z;
  y.w = (x.w-mu)*rstd*g.w + b.w;
  ((float4*)out)[(size_t)row*256 + t] = y;
}

// ---------------------------------------------------------------------------
// bt-GEMM mainloop, K-range parameterized. Single contiguous 32 KB LDS block
// (sA/sB as pointers) so epilogues can reuse it as a 128x128 bf16 tile.
// ---------------------------------------------------------------------------
#define GEMM_MAINLOOP_K(A_, Bt_, tM_, tN_, KLO_, KHI_)                          \
  __shared__ __align__(16) short smem_g[2*128*64];                              \
  short* sA = smem_g;                                                           \
  short* sB = smem_g + 128*64;                                                  \
  int t = threadIdx.x, w = t >> 6, lane = t & 63;                               \
  int wm = w & 1, wn = w >> 1, lm = lane & 15, q = lane >> 4;                   \
  int grow = lane >> 3;                                                         \
  int gchk = ((lane & 7) ^ grow) << 3;                                          \
  f32x4 acc[4][4] = {};                                                         \
  const unsigned short* Aw = A_ + (size_t)(tM_ + w*32 + grow)*1024 + gchk;      \
  const unsigned short* Bw = Bt_ + (size_t)(tN_ + w*32 + grow)*1024 + gchk;     \
  for (int kk = (KLO_); kk < (KHI_); kk += 64){                                 \
    __syncthreads();                                                            \
    gl2lds16(Aw + kk,            &sA[(w*32     )*64]);                          \
    gl2lds16(Aw + kk +  8*1024,  &sA[(w*32 +  8)*64]);                          \
    gl2lds16(Aw + kk + 16*1024,  &sA[(w*32 + 16)*64]);                          \
    gl2lds16(Aw + kk + 24*1024,  &sA[(w*32 + 24)*64]);                          \
    gl2lds16(Bw + kk,            &sB[(w*32     )*64]);                          \
    gl2lds16(Bw + kk +  8*1024,  &sB[(w*32 +  8)*64]);                          \
    gl2lds16(Bw + kk + 16*1024,  &sB[(w*32 + 16)*64]);                          \
    gl2lds16(Bw + kk + 24*1024,  &sB[(w*32 + 24)*64]);                          \
    __syncthreads();                                                            \
    bf16x8 af[4][2], bfr[4][2];                                                 \
    _Pragma("unroll")                                                           \
    for (int i = 0; i < 4; ++i){                                                \
      int ra = wm*64 + i*16 + lm, rb = wn*64 + i*16 + lm;                       \
      _Pragma("unroll")                                                         \
      for (int hh = 0; hh < 2; ++hh){                                           \
        int sw = ((hh*4 + q) ^ (lm & 7)) << 3;                                  \
        af[i][hh]  = *(const bf16x8*)(&sA[ra*64 + sw]);                         \
        bfr[i][hh] = *(const bf16x8*)(&sB[rb*64 + sw]);                         \
      }                                                                         \
    }                                                                           \
    _Pragma("unroll")                                                           \
    for (int hh = 0; hh < 2; ++hh)                                              \
      _Pragma("unroll")                                                         \
      for (int i = 0; i < 4; ++i)                                               \
        _Pragma("unroll")                                                       \
        for (int j = 0; j < 4; ++j)                                             \
          acc[i][j] = __builtin_amdgcn_mfma_f32_16x16x32_bf16(af[i][hh], bfr[j][hh], acc[i][j], 0, 0, 0); \
  }

#define GEMM_MAINLOOP(A_, Bt_, tM_, tN_) GEMM_MAINLOOP_K(A_, Bt_, tM_, tN_, 0, 1024)

// QKV GEMM (1D grid 768). XCD swizzle: 8 M-tiles x 12 N-tiles per XCD.
// V epilogue: LDS-transpose + coalesced 16B stores (was: ushort4 at 4KB
// lane stride = 8B useful per 64B granule -> ~8x write amplification).
__global__ __launch_bounds__(256) void gemm_qkv_kernel(
    const unsigned short* __restrict__ A, const unsigned short* __restrict__ Bt,
    unsigned short* __restrict__ Qb, unsigned short* __restrict__ Kb,
    unsigned short* __restrict__ VtG)
{
  int id = blockIdx.x;
  int xcd = id & 7, r = id >> 3;          // r in [0,96)
  int tM = ((xcd >> 1)*8 + (r & 7)) * 128;
  int tN = ((xcd & 1)*12 + (r >> 3)) * 128;   // [0,24) -> Q/K/V regions
  GEMM_MAINLOOP(A, Bt, tM, tN)
  if (tN < 1024){                 // Q region
    #pragma unroll
    for (int i = 0; i < 4; ++i){
      int R0 = tM + wm*64 + i*16 + q*4;
      int b = R0 >> 11, n = R0 & 2047;
      #pragma unroll
      for (int j = 0; j < 4; ++j){
        int Cg = tN + wn*64 + j*16 + lm;
        int h = Cg >> 6, d = Cg & 63;
        size_t base = ((((size_t)(b*16 + h) << 11) | n) << 6) + d;
        #pragma unroll
        for (int rr = 0; rr < 4; ++rr)
          Qb[base + (size_t)rr*64] = f2b(acc[i][j][rr] * QSCALE);
      }
    }
  } else if (tN < 2048){          // K region
    #pragma unroll
    for (int i = 0; i < 4; ++i){
      int R0 = tM + wm*64 + i*16 + q*4;
      int b = R0 >> 11, n = R0 & 2047;
      #pragma unroll
      for (int j = 0; j < 4; ++j){
        int c2 = tN - 1024 + wn*64 + j*16 + lm;
        int h = c2 >> 6, d = c2 & 63;
        size_t base = ((((size_t)(b*16 + h) << 11) | n) << 6) + d;
        #pragma unroll
        for (int rr = 0; rr < 4; ++rr)
          Kb[base + (size_t)rr*64] = f2b(acc[i][j][rr]);
      }
    }
  } else {                        // V region: LDS transpose + coalesced stores
    __syncthreads();              // last K-iter ds_reads done; smem_g is dead
    short* tileT = smem_g;        // 128 cols x 128 rows bf16, XOR-swz granules
    #pragma unroll
    for (int i = 0; i < 4; ++i){
      int r0 = wm*64 + i*16 + q*4;           // tile row of acc[i][.][0]
      int gr = r0 >> 3, ro = r0 & 7;         // ro in {0,4}: 4 rr stay in granule
      #pragma unroll
      for (int j = 0; j < 4; ++j){
        int col = wn*64 + j*16 + lm;         // tile col (= d dimension)
        u32x2 pkd;
        pkd[0] = pk2(acc[i][j][0], acc[i][j][1]);
        pkd[1] = pk2(acc[i][j][2], acc[i][j][3]);
        int gp = (gr ^ (col & 7)) << 3;      // swizzled granule
        *(u32x2*)(&tileT[col*128 + gp + ro]) = pkd;
      }
    }
    __syncthreads();
    int bb = tM >> 11, nb = tM & 2047;       // tile spans one b (tM 128-aligned)
    #pragma unroll
    for (int pp = 0; pp < 8; ++pp){
      int task = pp*256 + t;                 // 2048 tasks = 128 cols x 16 chunks
      int col = task >> 4, ch = task & 15;
      int cg = tN - 2048 + col;
      int h = cg >> 6, d = cg & 63;
      u32x4 v = *(const u32x4*)(&tileT[col*128 + ((ch ^ (col & 7)) << 3)]);
      *(u32x4*)(VtG + ((size_t)(bb*16 + h)*64 + d)*2048 + nb + ch*8) = v;
    }
  }
}

// Out-proj GEMM, split-K 2-way (kept from R8: non-attn time 198.5 -> 193.9).
__global__ __launch_bounds__(256) void gemm_out_kernel(
    const unsigned short* __restrict__ A, const unsigned short* __restrict__ Bt,
    float* __restrict__ C0, float* __restrict__ C1)
{
  int id = blockIdx.x;
  int xcd = id & 7, r = id >> 3;          // r in [0,64)
  int ks = r & 1;                          // K slice
  int r2 = r >> 1;                         // [0,32)
  int tM = ((r2 & 3)*8 + xcd) * 128;
  int tN = (r2 >> 2) * 128;                // [0,8)
  float* C = ks ? C1 : C0;
  GEMM_MAINLOOP_K(A, Bt, tM, tN, ks*512, ks*512 + 512)
  #pragma unroll
  for (int i = 0; i < 4; ++i){
    int R0 = tM + wm*64 + i*16 + q*4;
    #pragma unroll
    for (int j = 0; j < 4; ++j){
      int Cg = tN + wn*64 + j*16 + lm;
      #pragma unroll
      for (int rr = 0; rr < 4; ++rr)
        C[(size_t)(R0 + rr)*1024 + Cg] = acc[i][j][rr];
    }
  }
}

// ---------------------------------------------------------------------------
// Flash attention — R15 form, FROZEN (attn 64.0us, best of 7 experiments).
// R9 structure + s_setprio around MFMA clusters (R15 A/B: 64.0-64.4 vs
// 65.0-65.2 disjoint -> real ~1us win). 128-query blocks, grid 512, 2 pairs
// x 18/17 key tiles, additive no-max log2-softmax, merge in dead K/V LDS.
// LDS carve (40960 B): [0,16384) K | [16384,32768) Vt | [32768,40960) P.
// K/V: 64x64 shorts, granule g at g^(row&7) (write rsw=r0&7, read esw=lm&7).
// ---------------------------------------------------------------------------
__global__ __launch_bounds__(256, 2) void attn_kernel(
    const unsigned short* __restrict__ Qb, const unsigned short* __restrict__ Kb,
    const unsigned short* __restrict__ VtG, const unsigned short* __restrict__ kext,
    const unsigned short* __restrict__ vext_t, unsigned short* __restrict__ Ob)
{
  __shared__ __align__(16) char smem[40960];
  int id = blockIdx.x;
  int xcd = id & 7, slot = id >> 3;              // 4 bh per XCD for L2 locality
  int bh = xcd*4 + (slot >> 4);
  int qt = slot & 15;
  int b = bh >> 4, h = bh & 15;
  int t = threadIdx.x, w = t >> 6, lane = t & 63;
  int p = w >> 1, lw = w & 1;
  int lm = lane & 15, q = lane >> 4;
  int esw = lm & 7;                              // read-side swizzle key

  short* myK = (short*)(smem + p*8192);
  short* myV = (short*)(smem + 16384 + p*8192);
  short* pw  = (short*)(smem + 32768 + w*2048);

  const unsigned short* Qbase = Qb + ((size_t)bh*2048 + qt*128 + lw*64)*64;
  bf16x8 qf[4][2];
  #pragma unroll
  for (int qq = 0; qq < 4; ++qq){
    qf[qq][0] = *(const bf16x8*)(Qbase + (size_t)(qq*16 + lm)*64 + q*8);
    qf[qq][1] = *(const bf16x8*)(Qbase + (size_t)(qq*16 + lm)*64 + q*8 + 32);
  }

  f32x4 o[4][4] = {};                            // [ds][qq]
  float l_i[4] = {0.f, 0.f, 0.f, 0.f};

  // staging within the pair: 128 threads, row r0, 32-short half c0
  int pt = t & 127;
  int r0 = pt >> 1, c0 = (pt & 1) << 5;
  int rsw = r0 & 7;                              // write-side swizzle key
  const int t0 = p ? 18 : 0;
  const int t1 = p ? 35 : 18;

  u32x4 kr[4], vr[4];
  {
    const unsigned short* kp = Kb + ((size_t)bh*2048 + t0*64 + r0)*64 + c0;
    const unsigned short* vp = VtG + ((size_t)bh*64 + r0)*2048 + t0*64 + c0;
    #pragma unroll
    for (int jj = 0; jj < 4; ++jj){
      kr[jj] = *(const u32x4*)(kp + 8*jj);
      vr[jj] = *(const u32x4*)(vp + 8*jj);
    }
  }

  for (int it = 0; it < 18; ++it){
    int tile = t0 + it;
    bool valid = tile < t1;
    __syncthreads();
    if (valid){
      #pragma unroll
      for (int jj = 0; jj < 4; ++jj){
        int gsw = ((((pt & 1) << 2) | jj) ^ rsw) << 3;
        *(u32x4*)(&myK[r0*64 + gsw]) = kr[jj];
        *(u32x4*)(&myV[r0*64 + gsw]) = vr[jj];
      }
    }
    __syncthreads();

    int nt = tile + 1;
    if (nt < t1){                                // prefetch next tile
      bool ext = nt >= 32;
      int kb = ext ? (nt - 32)*64 : nt*64;
      const unsigned short* kp = ext ? (kext + ((size_t)b*192 + kb + r0)*64 + c0)
                                     : (Kb + ((size_t)bh*2048 + kb + r0)*64 + c0);
      const unsigned short* vp = ext ? (vext_t + ((size_t)b*64 + r0)*192 + kb + c0)
                                     : (VtG + ((size_t)bh*64 + r0)*2048 + kb + c0);
      #pragma unroll
      for (int jj = 0; jj < 4; ++jj){
        kr[jj] = *(const u32x4*)(kp + 8*jj);
        vr[jj] = *(const u32x4*)(vp + 8*jj);
      }
    }
    if (!valid) continue;                        // barriers already passed

    bf16x8 kf[4][2];
    #pragma unroll
    for (int st = 0; st < 4; ++st){
      kf[st][0] = *(const bf16x8*)(&myK[(st*16 + lm)*64 + ((q       ^ esw) << 3)]);
      kf[st][1] = *(const bf16x8*)(&myK[(st*16 + lm)*64 + (((4 + q) ^ esw) << 3)]);
    }

    #pragma unroll
    for (int qp = 0; qp < 2; ++qp){              // qq pairs {0,1},{2,3}
      f32x4 s[2][4];
      __builtin_amdgcn_s_setprio(1);             // QK^T MFMA cluster (m191)
      #pragma unroll
      for (int qh = 0; qh < 2; ++qh){
        int qq = qp*2 + qh;
        #pragma unroll
        for (int st = 0; st < 4; ++st){
          f32x4 z = {};
          z = __builtin_amdgcn_mfma_f32_16x16x32_bf16(kf[st][0], qf[qq][0], z, 0, 0, 0);
          s[qh][st] = __builtin_amdgcn_mfma_f32_16x16x32_bf16(kf[st][1], qf[qq][1], z, 0, 0, 0);
        }
      }
      __builtin_amdgcn_s_setprio(0);
      if (tile == 34){                           // keys 128..191: only 128 valid
        #pragma unroll
        for (int qh = 0; qh < 2; ++qh)
          #pragma unroll
          for (int st = 0; st < 4; ++st)
            #pragma unroll
            for (int rr = 0; rr < 4; ++rr){
              int key = 128 + st*16 + q*4 + rr;
              if (key >= 129) s[qh][st][rr] = -1e30f;
            }
      }
      bf16x8 pb[2][2];
      #pragma unroll
      for (int qh = 0; qh < 2; ++qh){            // per-qh: exp, pack->pw, read
        float sm = 0.f;
        #pragma unroll
        for (int st = 0; st < 4; ++st)
          #pragma unroll
          for (int rr = 0; rr < 4; ++rr){
            float pv = __builtin_amdgcn_exp2f(s[qh][st][rr]);
            s[qh][st][rr] = pv; sm += pv;
          }
        l_i[qp*2 + qh] += sm;
        #pragma unroll
        for (int st = 0; st < 4; ++st){
          u32x2 pkd;
          pkd[0] = pk2(s[qh][st][0], s[qh][st][1]);
          pkd[1] = pk2(s[qh][st][2], s[qh][st][3]);
          int gsw = ((((st << 1) | (q >> 1)) ^ esw) << 3) + ((q & 1) << 2);
          *(u32x2*)(&pw[lm*64 + gsw]) = pkd;
        }
        // read back (own-wave region, in-order DS pipe -> no barrier)
        bf16x4 a0 = *(const bf16x4*)(&pw[lm*64 + ((q       ^ esw) << 3)]);
        bf16x4 a1 = *(const bf16x4*)(&pw[lm*64 + ((q       ^ esw) << 3) + 4]);
        bf16x4 a2 = *(const bf16x4*)(&pw[lm*64 + (((4 + q) ^ esw) << 3)]);
        bf16x4 a3 = *(const bf16x4*)(&pw[lm*64 + (((4 + q) ^ esw) << 3) + 4]);
        pb[qh][0] = __builtin_shufflevector(a0, a1, 0,1,2,3,4,5,6,7);
        pb[qh][1] = __builtin_shufflevector(a2, a3, 0,1,2,3,4,5,6,7);
      }
      __builtin_amdgcn_s_setprio(1);             // PV MFMA cluster (m191)
      #pragma unroll
      for (int ds = 0; ds < 4; ++ds){
        bf16x8 af0 = *(const bf16x8*)(&myV[(ds*16 + lm)*64 + ((q       ^ esw) << 3)]);
        bf16x8 af1 = *(const bf16x8*)(&myV[(ds*16 + lm)*64 + (((4 + q) ^ esw) << 3)]);
        #pragma unroll
        for (int qh = 0; qh < 2; ++qh){
          int qq = qp*2 + qh;
          o[ds][qq] = __builtin_amdgcn_mfma_f32_16x16x32_bf16(af0, pb[qh][0], o[ds][qq], 0, 0, 0);
          o[ds][qq] = __builtin_amdgcn_mfma_f32_16x16x32_bf16(af1, pb[qh][1], o[ds][qq], 0, 0, 0);
        }
      }
      __builtin_amdgcn_s_setprio(0);
    }
  }

  // ---- merge the two key-halves (additive: no rescale needed) ----
  // overlay at smem offset 0: 2 waves x 64 lanes x 68 floats = 34816 B
  // (fits in the 40960 B allocation; K/Vt/P all dead past this barrier)
  float* mb = (float*)smem;
  float* reg = mb + lw*4352 + lane*68;
  __syncthreads();                               // all KV/P reads done
  if (p == 1){
    #pragma unroll
    for (int ds = 0; ds < 4; ++ds)
      #pragma unroll
      for (int qq = 0; qq < 4; ++qq)
        *(f32x4*)(reg + (ds*4 + qq)*4) = o[ds][qq];
    #pragma unroll
    for (int qq = 0; qq < 4; ++qq) reg[64 + qq] = l_i[qq];
  }
  __syncthreads();
  if (p == 0){
    #pragma unroll
    for (int qq = 0; qq < 4; ++qq){
      #pragma unroll
      for (int ds = 0; ds < 4; ++ds){
        f32x4 ov = *(const f32x4*)(reg + (ds*4 + qq)*4);
        o[ds][qq] += ov;
      }
      float l = l_i[qq] + reg[64 + qq];
      l += __shfl_xor(l, 16);
      l += __shfl_xor(l, 32);
      float inv = 1.0f / l;
      int n = qt*128 + lw*64 + qq*16 + lm;
      size_t base = ((size_t)b*2048 + n)*1024 + h*64 + q*4;
      #pragma unroll
      for (int ds = 0; ds < 4; ++ds){
        ushort4 u;
        u.x = f2b(o[ds][qq][0] * inv); u.y = f2b(o[ds][qq][1] * inv);
        u.z = f2b(o[ds][qq][2] * inv); u.w = f2b(o[ds][qq][3] * inv);
        *(ushort4*)(Ob + base + ds*16) = u;
      }
    }
  }
}

// ---------------------------------------------------------------------------
extern "C" void kernel_launch(void* const* d_in, const int* in_sizes, int n_in,
                              void* d_out, int out_size, void* d_ws, size_t ws_size,
                              hipStream_t stream)
{
  const float* x       = (const float*)d_in[0];
  const float* c_emb   = (const float*)d_in[1];
  const float* ln_g    = (const float*)d_in[2];
  const float* ln_b    = (const float*)d_in[3];
  const float* ctx_g   = (const float*)d_in[4];
  const float* ctx_b   = (const float*)d_in[5];
  const float* W_ctx   = (const float*)d_in[6];
  const float* b_ctx   = (const float*)d_in[7];
  const float* W_q     = (const float*)d_in[8];
  const float* W_kv    = (const float*)d_in[9];
  const float* null_kv = (const float*)d_in[10];
  const float* W_out   = (const float*)d_in[11];
  const float* oln_g   = (const float*)d_in[12];
  const float* oln_b   = (const float*)d_in[13];
  float* out = (float*)d_out;

  char* p = (char*)d_ws;
  unsigned short* xn     = (unsigned short*)p; p += (size_t)4096*1024*2;
  unsigned short* Wqkv_t = (unsigned short*)p; p += (size_t)3072*1024*2;
  unsigned short* Wout_t = (unsigned short*)p; p += (size_t)1024*1024*2;
  unsigned short* Qb     = (unsigned short*)p; p += (size_t)32*2048*64*2;
  unsigned short* Kb     = (unsigned short*)p; p += (size_t)32*2048*64*2;
  unsigned short* VtG    = (unsigned short*)p; p += (size_t)32*64*2048*2;
  unsigned short* kext   = (unsigned short*)p; p += (size_t)2*192*64*2;
  unsigned short* vext_t = (unsigned short*)p; p += (size_t)2*64*192*2;
  unsigned short* aout   = (unsigned short*)p; p += (size_t)4096*1024*2;
  float*          ptmp   = (float*)p;          p += (size_t)4096*1024*4;
  // split-K partial #2 overlays Qb+Kb (16 MB, dead after attn completes)
  float*          ptmp1  = (float*)Qb;

  prologue_kernel<<<5376, 256, 0, stream>>>(
      W_q, W_kv, W_out, Wqkv_t, Wout_t,
      x, ln_g, ln_b, xn,
      c_emb, ctx_g, ctx_b, W_ctx, b_ctx, null_kv, kext, vext_t);
  gemm_qkv_kernel<<<768, 256, 0, stream>>>(xn, Wqkv_t, Qb, Kb, VtG);
  attn_kernel<<<512, 256, 0, stream>>>(Qb, Kb, VtG, kext, vext_t, aout);
  gemm_out_kernel<<<512, 256, 0, stream>>>(aout, Wout_t, ptmp, ptmp1);
  ln1024f_kernel<<<4096, 256, 0, stream>>>(ptmp, ptmp1, oln_g, oln_b, out);
}